// Round 1
// baseline (130.409 us; speedup 1.0000x reference)
//
#include <hip/hip_runtime.h>

#define DEV static __device__ __forceinline__

typedef unsigned short u16;
typedef __bf16 bf16_t;
typedef __bf16 bf16x8 __attribute__((ext_vector_type(8)));
typedef float f32x4 __attribute__((ext_vector_type(4)));
typedef u16 u16x8 __attribute__((ext_vector_type(8)));

static constexpr int Bb = 8;     // batch
static constexpr int Nn = 4096;  // tokens per batch
static constexpr int Dd = 256;   // d
static constexpr int DP = 512;   // d_prime

// ---------------- async global->LDS (16B, wave-uniform LDS base + lane*16) ----------------
DEV void gload16(const void* g, void* l) {
  __builtin_amdgcn_global_load_lds(
      (__attribute__((address_space(1))) void*)(unsigned long long)(g),
      (__attribute__((address_space(3))) void*)(unsigned)(unsigned long long)(l),
      16, 0, 0);
}

DEV u16 f2bf(float x) { bf16_t h = (bf16_t)x; return __builtin_bit_cast(u16, h); }
DEV float gelu_exact(float x) { return 0.5f * x * (1.0f + erff(x * 0.70710678118654752f)); }

// ---------------- 128x128 tile mainloop, operands bf16 stored [rows][K] row-major ----------
// A: M-rows x K ; B: N-rows x K (i.e. B^T layout). 4 waves, each 64x64, 16x16x32 bf16 MFMA.
DEV void gemm_tile(const u16* Ag, int lda, const u16* Bg, int ldb,
                   int k0, int ksteps, u16* ldsA, u16* ldsB, f32x4 acc[4][4]) {
  const int tid  = threadIdx.x;
  const int wave = tid >> 6, lane = tid & 63;
  const int wr = wave >> 1, wc = wave & 1;
  const int lr = lane & 15, lk = (lane >> 4) * 8;
  const int srow = lane >> 2;          // 0..15 row within 16-row chunk
  const int skb  = (lane & 3) * 8;     // k element offset of this lane's 16B

  for (int kt = 0; kt < ksteps; ++kt) {
    const int kk = k0 + kt * 32;
#pragma unroll
    for (int i = 0; i < 2; ++i) {
      const int chunk = wave * 2 + i;          // 8 chunks of 16 rows each
      const int row = chunk * 16 + srow;
      gload16(Ag + (size_t)row * lda + kk + skb, ldsA + chunk * 512);
      gload16(Bg + (size_t)row * ldb + kk + skb, ldsB + chunk * 512);
    }
    asm volatile("s_waitcnt vmcnt(0)" ::: "memory");
    __syncthreads();
    bf16x8 af[4], bfr[4];
#pragma unroll
    for (int m = 0; m < 4; ++m)
      af[m] = *(const bf16x8*)(ldsA + (wr * 64 + m * 16 + lr) * 32 + lk);
#pragma unroll
    for (int n = 0; n < 4; ++n)
      bfr[n] = *(const bf16x8*)(ldsB + (wc * 64 + n * 16 + lr) * 32 + lk);
#pragma unroll
    for (int m = 0; m < 4; ++m)
#pragma unroll
      for (int n = 0; n < 4; ++n)
        acc[m][n] = __builtin_amdgcn_mfma_f32_16x16x32_bf16(af[m], bfr[n], acc[m][n], 0, 0, 0);
    __syncthreads();
  }
}

DEV void acc_zero(f32x4 acc[4][4]) {
#pragma unroll
  for (int m = 0; m < 4; ++m)
#pragma unroll
    for (int n = 0; n < 4; ++n) {
      f32x4 z = {0.f, 0.f, 0.f, 0.f};
      acc[m][n] = z;
    }
}

// ---------------- kernel: Xp = bf16(X+P), plus XpT (per-batch [d][n]) ----------------
__global__ __launch_bounds__(256) void k_xp(const float* __restrict__ X, const float* __restrict__ P,
                                            u16* __restrict__ Xp, u16* __restrict__ XpT) {
  __shared__ u16 lt[64 * 65];
  const int bid = blockIdx.x;
  const int b  = bid >> 8;
  const int nt = (bid >> 2) & 63;
  const int dt = bid & 3;
  const int n0 = nt * 64, d0 = dt * 64;
  const int t = threadIdx.x;
  const int r = t >> 2, c0 = (t & 3) * 16;
  const size_t gbase = ((size_t)(b * Nn + n0 + r)) * Dd + d0 + c0;
  u16x8 lo, hi;
#pragma unroll
  for (int i = 0; i < 4; ++i) {
    float4 xv = *(const float4*)(X + gbase + i * 4);
    float4 pv = *(const float4*)(P + gbase + i * 4);
    u16 a0 = f2bf(xv.x + pv.x), a1 = f2bf(xv.y + pv.y);
    u16 a2 = f2bf(xv.z + pv.z), a3 = f2bf(xv.w + pv.w);
    if (i < 2) { lo[i*4+0]=a0; lo[i*4+1]=a1; lo[i*4+2]=a2; lo[i*4+3]=a3; }
    else       { int q=(i-2)*4; hi[q+0]=a0; hi[q+1]=a1; hi[q+2]=a2; hi[q+3]=a3; }
    lt[r * 65 + c0 + i*4 + 0] = a0; lt[r * 65 + c0 + i*4 + 1] = a1;
    lt[r * 65 + c0 + i*4 + 2] = a2; lt[r * 65 + c0 + i*4 + 3] = a3;
  }
  *(u16x8*)(Xp + gbase)     = lo;
  *(u16x8*)(Xp + gbase + 8) = hi;
  __syncthreads();
  const int dd = t >> 2, nc0 = (t & 3) * 16;
  u16x8 olo, ohi;
#pragma unroll
  for (int i = 0; i < 8; ++i) olo[i] = lt[(nc0 + i) * 65 + dd];
#pragma unroll
  for (int i = 0; i < 8; ++i) ohi[i] = lt[(nc0 + 8 + i) * 65 + dd];
  const size_t obase = ((size_t)(b * Dd + d0 + dd)) * Nn + n0 + nc0;
  *(u16x8*)(XpT + obase)     = olo;
  *(u16x8*)(XpT + obase + 8) = ohi;
}

// ---------------- kernel: WhT[w][p][d] = bf16(Wh_w[d][p]) ----------------
__global__ __launch_bounds__(256) void k_wht(const float* __restrict__ Wh1, const float* __restrict__ Wh2,
                                             u16* __restrict__ WhT) {
  __shared__ u16 lt[64 * 65];
  const int bid = blockIdx.x;         // 2 * 4(dtiles) * 8(ptiles)
  const int w  = bid >> 5;
  const int rt = (bid >> 3) & 3;      // d tile
  const int ct = bid & 7;             // p tile
  const float* src = w ? Wh2 : Wh1;
  const int r0 = rt * 64, c0t = ct * 64;
  const int t = threadIdx.x;
  const int r = t >> 2, c0 = (t & 3) * 16;
  const size_t gbase = (size_t)(r0 + r) * DP + c0t + c0;
#pragma unroll
  for (int i = 0; i < 4; ++i) {
    float4 v = *(const float4*)(src + gbase + i * 4);
    lt[r * 65 + c0 + i*4 + 0] = f2bf(v.x); lt[r * 65 + c0 + i*4 + 1] = f2bf(v.y);
    lt[r * 65 + c0 + i*4 + 2] = f2bf(v.z); lt[r * 65 + c0 + i*4 + 3] = f2bf(v.w);
  }
  __syncthreads();
  const int pp = t >> 2, dc0 = (t & 3) * 16;
  u16x8 olo, ohi;
#pragma unroll
  for (int i = 0; i < 8; ++i) olo[i] = lt[(dc0 + i) * 65 + pp];
#pragma unroll
  for (int i = 0; i < 8; ++i) ohi[i] = lt[(dc0 + 8 + i) * 65 + pp];
  u16* out = WhT + (size_t)(w * DP + c0t + pp) * Dd + r0 + dc0;
  *(u16x8*)(out)     = olo;
  *(u16x8*)(out + 8) = ohi;
}

// ---------------- kernel: W = Xp @ WhT^T + bh ; W1 stored transposed, W2 normal ----------
__global__ __launch_bounds__(256) void k_gemmB(const u16* __restrict__ Xp, const u16* __restrict__ WhT,
                                               const float* __restrict__ bh1, const float* __restrict__ bh2,
                                               u16* __restrict__ W1T, u16* __restrict__ W2) {
  __shared__ __align__(16) u16 ldsA[128 * 32];
  __shared__ __align__(16) u16 ldsB[128 * 32];
  __shared__ __align__(16) u16 ct[128 * 136];
  const int bid = blockIdx.x;
  const int tm = bid >> 3, tn = bid & 7;
  const bool isW1 = tn < 4;
  const int p0 = (isW1 ? tn : tn - 4) * 128;
  const u16* Ag = Xp + (size_t)tm * 128 * Dd;
  const u16* Bg = WhT + (size_t)((isW1 ? 0 : 1) * DP + p0) * Dd;
  const float* bh = isW1 ? bh1 : bh2;
  f32x4 acc[4][4];
  acc_zero(acc);
  gemm_tile(Ag, Dd, Bg, Dd, 0, Dd / 32, ldsA, ldsB, acc);
  const int tid = threadIdx.x, wave = tid >> 6, lane = tid & 63;
  const int wr = wave >> 1, wc = wave & 1, lr = lane & 15, lq = lane >> 4;
  if (isW1) {
#pragma unroll
    for (int n = 0; n < 4; ++n) {
      const int col = wc * 64 + n * 16 + lr;          // p within tile
      const float bv = bh[p0 + col];
#pragma unroll
      for (int m = 0; m < 4; ++m)
#pragma unroll
        for (int j = 0; j < 4; ++j)
          ct[col * 136 + wr * 64 + m * 16 + lq * 4 + j] = f2bf(acc[m][n][j] + bv);
    }
    __syncthreads();
    const int tok0 = tm * 128;
    const int beta = tok0 >> 12, nloc = tok0 & 4095;
#pragma unroll
    for (int it = 0; it < 8; ++it) {
      const int id = tid + it * 256;
      const int p = id >> 4, ch = id & 15;
      *(u16x8*)(W1T + (size_t)(beta * DP + p0 + p) * Nn + nloc + ch * 8) =
          *(const u16x8*)(ct + p * 136 + ch * 8);
    }
  } else {
    const size_t row0 = (size_t)tm * 128;
#pragma unroll
    for (int n = 0; n < 4; ++n) {
      const int col = wc * 64 + n * 16 + lr;
      const float bv = bh[p0 + col];
#pragma unroll
      for (int m = 0; m < 4; ++m)
#pragma unroll
        for (int j = 0; j < 4; ++j)
          W2[(row0 + wr * 64 + m * 16 + lq * 4 + j) * DP + p0 + col] = f2bf(acc[m][n][j] + bv);
    }
  }
}

// ---------------- kernel: Pm[b][p][d] += split-K of W1T[b] @ XpT[b]^T ----------------
__global__ __launch_bounds__(256) void k_gemm3(const u16* __restrict__ W1T, const u16* __restrict__ XpT,
                                               float* __restrict__ Pm) {
  __shared__ __align__(16) u16 ldsA[128 * 32];
  __shared__ __align__(16) u16 ldsB[128 * 32];
  const int bid = blockIdx.x;           // 8b * 4tm * 2tn * 8kc
  const int kc = bid & 7;
  const int tn = (bid >> 3) & 1;
  const int tm = (bid >> 4) & 3;
  const int b  = bid >> 6;
  const u16* Ag = W1T + (size_t)(b * DP + tm * 128) * Nn;
  const u16* Bg = XpT + (size_t)(b * Dd + tn * 128) * Nn;
  f32x4 acc[4][4];
  acc_zero(acc);
  gemm_tile(Ag, Nn, Bg, Nn, kc * 512, 16, ldsA, ldsB, acc);
  const int tid = threadIdx.x, wave = tid >> 6, lane = tid & 63;
  const int wr = wave >> 1, wc = wave & 1, lr = lane & 15, lq = lane >> 4;
  float* base = Pm + (size_t)(b * DP + tm * 128) * Dd + tn * 128;
#pragma unroll
  for (int m = 0; m < 4; ++m)
#pragma unroll
    for (int n = 0; n < 4; ++n)
#pragma unroll
      for (int j = 0; j < 4; ++j)
        atomicAdd(base + (size_t)(wr * 64 + m * 16 + lq * 4 + j) * Dd + wc * 64 + n * 16 + lr,
                  acc[m][n][j]);
}

// ---------------- kernel: GT[b][d][p] = bf16(gelu(Pm[b][p][d])) ----------------
__global__ __launch_bounds__(256) void k_gelu(const float* __restrict__ Pm, u16* __restrict__ GT) {
  __shared__ u16 lt[64 * 65];
  const int bid = blockIdx.x;        // 8b * 8pt * 4dt
  const int b  = bid >> 5;
  const int pt = (bid >> 2) & 7;
  const int dt = bid & 3;
  const int p0 = pt * 64, d0 = dt * 64;
  const int t = threadIdx.x;
  const int r = t >> 2, c0 = (t & 3) * 16;
  const size_t gbase = (size_t)(b * DP + p0 + r) * Dd + d0 + c0;
#pragma unroll
  for (int i = 0; i < 4; ++i) {
    float4 v = *(const float4*)(Pm + gbase + i * 4);
    lt[r * 65 + c0 + i*4 + 0] = f2bf(gelu_exact(v.x));
    lt[r * 65 + c0 + i*4 + 1] = f2bf(gelu_exact(v.y));
    lt[r * 65 + c0 + i*4 + 2] = f2bf(gelu_exact(v.z));
    lt[r * 65 + c0 + i*4 + 3] = f2bf(gelu_exact(v.w));
  }
  __syncthreads();
  const int dd = t >> 2, pc0 = (t & 3) * 16;
  u16x8 olo, ohi;
#pragma unroll
  for (int i = 0; i < 8; ++i) olo[i] = lt[(pc0 + i) * 65 + dd];
#pragma unroll
  for (int i = 0; i < 8; ++i) ohi[i] = lt[(pc0 + 8 + i) * 65 + dd];
  u16* out = GT + (size_t)(b * Dd + d0 + dd) * DP + p0 + pc0;
  *(u16x8*)(out)     = olo;
  *(u16x8*)(out + 8) = ohi;
}

// ---------------- kernel: Y[b][n][d] = W2[b] @ GT[b]^T ----------------
__global__ __launch_bounds__(256) void k_gemm4(const u16* __restrict__ W2, const u16* __restrict__ GT,
                                               float* __restrict__ Y) {
  __shared__ __align__(16) u16 ldsA[128 * 32];
  __shared__ __align__(16) u16 ldsB[128 * 32];
  const int bid = blockIdx.x;      // 8b * 32tm * 2tn
  const int tn = bid & 1;
  const int tm = (bid >> 1) & 31;
  const int b  = bid >> 6;
  const u16* Ag = W2 + (size_t)(b * Nn + tm * 128) * DP;
  const u16* Bg = GT + (size_t)(b * Dd + tn * 128) * DP;
  f32x4 acc[4][4];
  acc_zero(acc);
  gemm_tile(Ag, DP, Bg, DP, 0, DP / 32, ldsA, ldsB, acc);
  const int tid = threadIdx.x, wave = tid >> 6, lane = tid & 63;
  const int wr = wave >> 1, wc = wave & 1, lr = lane & 15, lq = lane >> 4;
  float* base = Y + (size_t)(b * Nn + tm * 128) * Dd + tn * 128;
#pragma unroll
  for (int m = 0; m < 4; ++m)
#pragma unroll
    for (int n = 0; n < 4; ++n)
#pragma unroll
      for (int j = 0; j < 4; ++j)
        base[(size_t)(wr * 64 + m * 16 + lq * 4 + j) * Dd + wc * 64 + n * 16 + lr] = acc[m][n][j];
}

// ---------------- launcher ----------------
extern "C" void kernel_launch(void* const* d_in, const int* in_sizes, int n_in,
                              void* d_out, int out_size, void* d_ws, size_t ws_size,
                              hipStream_t stream) {
  const float* X   = (const float*)d_in[0];
  const float* P   = (const float*)d_in[1];
  const float* Wh1 = (const float*)d_in[2];
  const float* bh1 = (const float*)d_in[3];
  const float* Wh2 = (const float*)d_in[4];
  const float* bh2 = (const float*)d_in[5];
  float* Y = (float*)d_out;
  char* ws = (char*)d_ws;

  // workspace layout (bytes); Pm/GT overlay the Xp region (Xp dead after k_gemmB)
  u16*   Xp  = (u16*)(ws);                    // 16,777,216 B
  float* Pm  = (float*)(ws);                  //  4,194,304 B (overlay, used after gemmB)
  u16*   GT  = (u16*)(ws + 4194304);          //  2,097,152 B (overlay)
  u16*   XpT = (u16*)(ws + 16777216);         // 16,777,216 B
  u16*   W1T = (u16*)(ws + 33554432);         // 33,554,432 B
  u16*   W2  = (u16*)(ws + 67108864);         // 33,554,432 B
  u16*   WhT = (u16*)(ws + 100663296);        //    524,288 B
  const size_t WS_NEED = 101187584;
  if (ws_size < WS_NEED) return;  // not enough scratch — bail (will show as absmax fail)

  k_wht  <<<64,   256, 0, stream>>>(Wh1, Wh2, WhT);
  k_xp   <<<2048, 256, 0, stream>>>(X, P, Xp, XpT);
  k_gemmB<<<2048, 256, 0, stream>>>(Xp, WhT, bh1, bh2, W1T, W2);
  hipMemsetAsync(Pm, 0, (size_t)Bb * DP * Dd * sizeof(float), stream);
  k_gemm3<<<512,  256, 0, stream>>>(W1T, XpT, Pm);
  k_gelu <<<256,  256, 0, stream>>>(Pm, GT);
  k_gemm4<<<512,  256, 0, stream>>>(W2, GT, Y);
}

// Round 2
// 100.671 us; speedup vs baseline: 1.2954x; 1.2954x over previous
//
#include <hip/hip_runtime.h>

#define DEV static __device__ __forceinline__

typedef unsigned short u16;
typedef __bf16 bf16_t;
typedef __bf16 bf16x8 __attribute__((ext_vector_type(8)));
typedef float f32x4 __attribute__((ext_vector_type(4)));
typedef u16 u16x8 __attribute__((ext_vector_type(8)));

static constexpr int Bb = 8;     // batch
static constexpr int Nn = 4096;  // tokens per batch
static constexpr int Dd = 256;   // d
static constexpr int DP = 512;   // d_prime

// ---------------- async global->LDS (16B, wave-uniform LDS base + lane*16) ----------------
DEV void gload16(const void* g, void* l) {
  __builtin_amdgcn_global_load_lds(
      (__attribute__((address_space(1))) void*)(unsigned long long)(g),
      (__attribute__((address_space(3))) void*)(unsigned)(unsigned long long)(l),
      16, 0, 0);
}

DEV u16 f2bf(float x) { bf16_t h = (bf16_t)x; return __builtin_bit_cast(u16, h); }
DEV float bf2f(u16 v) { unsigned u = ((unsigned)v) << 16; return __builtin_bit_cast(float, u); }
DEV float gelu_exact(float x) { return 0.5f * x * (1.0f + erff(x * 0.70710678118654752f)); }

// ---------------- 128x128 tile mainloop, operands bf16 stored [rows][K] row-major ----------
// A: M-rows x K ; B: N-rows x K (i.e. B^T layout). 4 waves, each 64x64, 16x16x32 bf16 MFMA.
DEV void gemm_tile(const u16* Ag, int lda, const u16* Bg, int ldb,
                   int k0, int ksteps, u16* ldsA, u16* ldsB, f32x4 acc[4][4]) {
  const int tid  = threadIdx.x;
  const int wave = tid >> 6, lane = tid & 63;
  const int wr = wave >> 1, wc = wave & 1;
  const int lr = lane & 15, lk = (lane >> 4) * 8;
  const int srow = lane >> 2;          // 0..15 row within 16-row chunk
  const int skb  = (lane & 3) * 8;     // k element offset of this lane's 16B

  for (int kt = 0; kt < ksteps; ++kt) {
    const int kk = k0 + kt * 32;
#pragma unroll
    for (int i = 0; i < 2; ++i) {
      const int chunk = wave * 2 + i;          // 8 chunks of 16 rows each
      const int row = chunk * 16 + srow;
      gload16(Ag + (size_t)row * lda + kk + skb, ldsA + chunk * 512);
      gload16(Bg + (size_t)row * ldb + kk + skb, ldsB + chunk * 512);
    }
    asm volatile("s_waitcnt vmcnt(0)" ::: "memory");
    __syncthreads();
    bf16x8 af[4], bfr[4];
#pragma unroll
    for (int m = 0; m < 4; ++m)
      af[m] = *(const bf16x8*)(ldsA + (wr * 64 + m * 16 + lr) * 32 + lk);
#pragma unroll
    for (int n = 0; n < 4; ++n)
      bfr[n] = *(const bf16x8*)(ldsB + (wc * 64 + n * 16 + lr) * 32 + lk);
#pragma unroll
    for (int m = 0; m < 4; ++m)
#pragma unroll
      for (int n = 0; n < 4; ++n)
        acc[m][n] = __builtin_amdgcn_mfma_f32_16x16x32_bf16(af[m], bfr[n], acc[m][n], 0, 0, 0);
    __syncthreads();
  }
}

DEV void acc_zero(f32x4 acc[4][4]) {
#pragma unroll
  for (int m = 0; m < 4; ++m)
#pragma unroll
    for (int n = 0; n < 4; ++n) {
      f32x4 z = {0.f, 0.f, 0.f, 0.f};
      acc[m][n] = z;
    }
}

// ---------------- kernel: Xp = bf16(X+P) [b,n,d], XpT [b,d,n], s[b,d] = sum_n Xp ----------
__global__ __launch_bounds__(256) void k_xp(const float* __restrict__ X, const float* __restrict__ P,
                                            u16* __restrict__ Xp, u16* __restrict__ XpT,
                                            float* __restrict__ s) {
  __shared__ u16 lt[64 * 65];
  const int bid = blockIdx.x;
  const int b  = bid >> 8;
  const int nt = (bid >> 2) & 63;
  const int dt = bid & 3;
  const int n0 = nt * 64, d0 = dt * 64;
  const int t = threadIdx.x;
  const int r = t >> 2, c0 = (t & 3) * 16;
  const size_t gbase = ((size_t)(b * Nn + n0 + r)) * Dd + d0 + c0;
  u16x8 lo, hi;
#pragma unroll
  for (int i = 0; i < 4; ++i) {
    float4 xv = *(const float4*)(X + gbase + i * 4);
    float4 pv = *(const float4*)(P + gbase + i * 4);
    u16 a0 = f2bf(xv.x + pv.x), a1 = f2bf(xv.y + pv.y);
    u16 a2 = f2bf(xv.z + pv.z), a3 = f2bf(xv.w + pv.w);
    if (i < 2) { lo[i*4+0]=a0; lo[i*4+1]=a1; lo[i*4+2]=a2; lo[i*4+3]=a3; }
    else       { int q=(i-2)*4; hi[q+0]=a0; hi[q+1]=a1; hi[q+2]=a2; hi[q+3]=a3; }
    lt[r * 65 + c0 + i*4 + 0] = a0; lt[r * 65 + c0 + i*4 + 1] = a1;
    lt[r * 65 + c0 + i*4 + 2] = a2; lt[r * 65 + c0 + i*4 + 3] = a3;
  }
  *(u16x8*)(Xp + gbase)     = lo;
  *(u16x8*)(Xp + gbase + 8) = hi;
  __syncthreads();
  const int dd = t >> 2, nc0 = (t & 3) * 16;
  u16x8 olo, ohi;
  float colsum = 0.f;
#pragma unroll
  for (int i = 0; i < 8; ++i) { olo[i] = lt[(nc0 + i) * 65 + dd]; colsum += bf2f(olo[i]); }
#pragma unroll
  for (int i = 0; i < 8; ++i) { ohi[i] = lt[(nc0 + 8 + i) * 65 + dd]; colsum += bf2f(ohi[i]); }
  const size_t obase = ((size_t)(b * Dd + d0 + dd)) * Nn + n0 + nc0;
  *(u16x8*)(XpT + obase)     = olo;
  *(u16x8*)(XpT + obase + 8) = ohi;
  colsum += __shfl_xor(colsum, 1);
  colsum += __shfl_xor(colsum, 2);
  if ((t & 3) == 0) atomicAdd(s + b * Dd + d0 + dd, colsum);
}

// ---------------- kernel: WhT1[p][d] = bf16(Wh1[d][p]);  Wbf2 = bf16(Wh2) ----------------
__global__ __launch_bounds__(256) void k_wprep(const float* __restrict__ Wh1, const float* __restrict__ Wh2,
                                               u16* __restrict__ WhT1, u16* __restrict__ Wbf2) {
  const int bid = blockIdx.x;
  const int t = threadIdx.x;
  if (bid < 32) {  // transpose Wh1 [256][512] -> WhT1 [512][256]
    __shared__ u16 lt[64 * 65];
    const int rt = (bid >> 3) & 3;      // d tile
    const int ct = bid & 7;             // p tile
    const int r0 = rt * 64, c0t = ct * 64;
    const int r = t >> 2, c0 = (t & 3) * 16;
    const size_t gbase = (size_t)(r0 + r) * DP + c0t + c0;
#pragma unroll
    for (int i = 0; i < 4; ++i) {
      float4 v = *(const float4*)(Wh1 + gbase + i * 4);
      lt[r * 65 + c0 + i*4 + 0] = f2bf(v.x); lt[r * 65 + c0 + i*4 + 1] = f2bf(v.y);
      lt[r * 65 + c0 + i*4 + 2] = f2bf(v.z); lt[r * 65 + c0 + i*4 + 3] = f2bf(v.w);
    }
    __syncthreads();
    const int pp = t >> 2, dc0 = (t & 3) * 16;
    u16x8 olo, ohi;
#pragma unroll
    for (int i = 0; i < 8; ++i) olo[i] = lt[(dc0 + i) * 65 + pp];
#pragma unroll
    for (int i = 0; i < 8; ++i) ohi[i] = lt[(dc0 + 8 + i) * 65 + pp];
    u16* out = WhT1 + (size_t)(c0t + pp) * Dd + r0 + dc0;
    *(u16x8*)(out)     = olo;
    *(u16x8*)(out + 8) = ohi;
  } else {         // straight cast Wh2 -> Wbf2
    const int idx = ((bid - 32) * 256 + t) * 8;
    float4 v0 = *(const float4*)(Wh2 + idx);
    float4 v1 = *(const float4*)(Wh2 + idx + 4);
    u16x8 o;
    o[0]=f2bf(v0.x); o[1]=f2bf(v0.y); o[2]=f2bf(v0.z); o[3]=f2bf(v0.w);
    o[4]=f2bf(v1.x); o[5]=f2bf(v1.y); o[6]=f2bf(v1.z); o[7]=f2bf(v1.w);
    *(u16x8*)(Wbf2 + idx) = o;
  }
}

// ---------------- kernel: G[b] += split-K of XpT[b] @ XpT[b]^T (Gram, f32 atomic) --------
__global__ __launch_bounds__(256) void k_gram(const u16* __restrict__ XpT, float* __restrict__ G) {
  __shared__ __align__(16) u16 ldsA[128 * 32];
  __shared__ __align__(16) u16 ldsB[128 * 32];
  const int bid = blockIdx.x;           // 8b * 2tm * 2tn * 8kc
  const int kc = bid & 7;
  const int tn = (bid >> 3) & 1;
  const int tm = (bid >> 4) & 1;
  const int b  = bid >> 5;
  const u16* Ag = XpT + (size_t)(b * Dd + tm * 128) * Nn;
  const u16* Bg = XpT + (size_t)(b * Dd + tn * 128) * Nn;
  f32x4 acc[4][4];
  acc_zero(acc);
  gemm_tile(Ag, Nn, Bg, Nn, kc * 512, 16, ldsA, ldsB, acc);
  const int tid = threadIdx.x, wave = tid >> 6, lane = tid & 63;
  const int wr = wave >> 1, wc = wave & 1, lr = lane & 15, lq = lane >> 4;
  float* base = G + (size_t)(b * Dd + tm * 128) * Dd + tn * 128;
#pragma unroll
  for (int m = 0; m < 4; ++m)
#pragma unroll
    for (int n = 0; n < 4; ++n)
#pragma unroll
      for (int j = 0; j < 4; ++j)
        atomicAdd(base + (size_t)(wr * 64 + m * 16 + lq * 4 + j) * Dd + wc * 64 + n * 16 + lr,
                  acc[m][n][j]);
}

// ---------------- kernel: Gb = bf16(G) ----------------
__global__ __launch_bounds__(256) void k_gcast(const float* __restrict__ G, u16* __restrict__ Gb) {
  const int idx = (blockIdx.x * 256 + threadIdx.x) * 8;
  float4 v0 = *(const float4*)(G + idx);
  float4 v1 = *(const float4*)(G + idx + 4);
  u16x8 o;
  o[0]=f2bf(v0.x); o[1]=f2bf(v0.y); o[2]=f2bf(v0.z); o[3]=f2bf(v0.w);
  o[4]=f2bf(v1.x); o[5]=f2bf(v1.y); o[6]=f2bf(v1.z); o[7]=f2bf(v1.w);
  *(u16x8*)(Gb + idx) = o;
}

// -------- kernel: AT[b][d][p] = bf16(gelu(Wh1^T G + bh1 ⊗ s)) (Pm computed on the fly) ----
__global__ __launch_bounds__(256) void k_pmAT(const u16* __restrict__ WhT1, const u16* __restrict__ Gb,
                                              const float* __restrict__ bh1, const float* __restrict__ s,
                                              u16* __restrict__ AT) {
  __shared__ __align__(16) u16 ldsA[128 * 32];
  __shared__ __align__(16) u16 ldsB[128 * 32];
  __shared__ __align__(16) u16 ct[128 * 136];
  const int bid = blockIdx.x;        // 8b * 4tm(p) * 2tn(d)
  const int tn = bid & 1;
  const int tm = (bid >> 1) & 3;
  const int b  = bid >> 3;
  const int p0 = tm * 128, d0 = tn * 128;
  const u16* Ag = WhT1 + (size_t)p0 * Dd;                    // rows p, K=d
  const u16* Bg = Gb + (size_t)(b * Dd + d0) * Dd;           // rows d_out, K=d (G symmetric)
  f32x4 acc[4][4];
  acc_zero(acc);
  gemm_tile(Ag, Dd, Bg, Dd, 0, Dd / 32, ldsA, ldsB, acc);
  const int tid = threadIdx.x, wave = tid >> 6, lane = tid & 63;
  const int wr = wave >> 1, wc = wave & 1, lr = lane & 15, lq = lane >> 4;
#pragma unroll
  for (int n = 0; n < 4; ++n) {
    const int col = wc * 64 + n * 16 + lr;              // d within tile
    const float sv = s[b * Dd + d0 + col];
#pragma unroll
    for (int m = 0; m < 4; ++m) {
#pragma unroll
      for (int j = 0; j < 4; ++j) {
        const int row = wr * 64 + m * 16 + lq * 4 + j;  // p within tile
        const float pm = acc[m][n][j] + bh1[p0 + row] * sv;
        ct[col * 136 + row] = f2bf(gelu_exact(pm));
      }
    }
  }
  __syncthreads();
#pragma unroll
  for (int it = 0; it < 8; ++it) {
    const int id = tid + it * 256;
    const int dl = id >> 4, ch = id & 15;
    *(u16x8*)(AT + (size_t)(b * Dd + d0 + dl) * DP + p0 + ch * 8) =
        *(const u16x8*)(ct + dl * 136 + ch * 8);
  }
}

// ---------------- kernel: c[b][d] = sum_p bh2[p] * AT[b][d][p] ----------------
__global__ __launch_bounds__(64) void k_c(const u16* __restrict__ AT, const float* __restrict__ bh2,
                                          float* __restrict__ c) {
  const int bid = blockIdx.x;     // 8b * 256d
  const int b = bid >> 8, d = bid & 255;
  const int lane = threadIdx.x;
  u16x8 v = *(const u16x8*)(AT + (size_t)(b * Dd + d) * DP + lane * 8);
  float sum = 0.f;
#pragma unroll
  for (int i = 0; i < 8; ++i) sum += bh2[lane * 8 + i] * bf2f(v[i]);
#pragma unroll
  for (int off = 1; off < 64; off <<= 1) sum += __shfl_xor(sum, off);
  if (lane == 0) c[b * Dd + d] = sum;
}

// ---------------- kernel: HT[b][d_out][kd] = bf16(Wh2 @ A)^T ----------------
__global__ __launch_bounds__(256) void k_h(const u16* __restrict__ Wbf2, const u16* __restrict__ AT,
                                           u16* __restrict__ HT) {
  __shared__ __align__(16) u16 ldsA[128 * 32];
  __shared__ __align__(16) u16 ldsB[128 * 32];
  __shared__ __align__(16) u16 ct[128 * 136];
  const int bid = blockIdx.x;        // 8b * 2tm(kd) * 2tn(d_out)
  const int tn = bid & 1;
  const int tm = (bid >> 1) & 1;
  const int b  = bid >> 2;
  const int k0 = tm * 128, d0 = tn * 128;
  const u16* Ag = Wbf2 + (size_t)k0 * DP;                    // rows kd, K=p
  const u16* Bg = AT + (size_t)(b * Dd + d0) * DP;           // rows d_out, K=p
  f32x4 acc[4][4];
  acc_zero(acc);
  gemm_tile(Ag, DP, Bg, DP, 0, DP / 32, ldsA, ldsB, acc);
  const int tid = threadIdx.x, wave = tid >> 6, lane = tid & 63;
  const int wr = wave >> 1, wc = wave & 1, lr = lane & 15, lq = lane >> 4;
#pragma unroll
  for (int n = 0; n < 4; ++n) {
    const int col = wc * 64 + n * 16 + lr;              // d_out within tile
#pragma unroll
    for (int m = 0; m < 4; ++m)
#pragma unroll
      for (int j = 0; j < 4; ++j)
        ct[col * 136 + wr * 64 + m * 16 + lq * 4 + j] = f2bf(acc[m][n][j]);
  }
  __syncthreads();
#pragma unroll
  for (int it = 0; it < 8; ++it) {
    const int id = tid + it * 256;
    const int dl = id >> 4, ch = id & 15;
    *(u16x8*)(HT + (size_t)(b * Dd + d0 + dl) * Dd + k0 + ch * 8) =
        *(const u16x8*)(ct + dl * 136 + ch * 8);
  }
}

// ---------------- kernel: Y[b][n][d] = Xp[b] @ H[b] + c[b][d] ----------------
__global__ __launch_bounds__(256) void k_y(const u16* __restrict__ Xp, const u16* __restrict__ HT,
                                           const float* __restrict__ c, float* __restrict__ Y) {
  __shared__ __align__(16) u16 ldsA[128 * 32];
  __shared__ __align__(16) u16 ldsB[128 * 32];
  const int bid = blockIdx.x;      // 8b * 32tm * 2tn
  const int tn = bid & 1;
  const int tm = (bid >> 1) & 31;
  const int b  = bid >> 6;
  const u16* Ag = Xp + (size_t)(b * Nn + tm * 128) * Dd;
  const u16* Bg = HT + (size_t)(b * Dd + tn * 128) * Dd;
  f32x4 acc[4][4];
  acc_zero(acc);
  gemm_tile(Ag, Dd, Bg, Dd, 0, Dd / 32, ldsA, ldsB, acc);
  const int tid = threadIdx.x, wave = tid >> 6, lane = tid & 63;
  const int wr = wave >> 1, wc = wave & 1, lr = lane & 15, lq = lane >> 4;
  float* base = Y + (size_t)(b * Nn + tm * 128) * Dd + tn * 128;
#pragma unroll
  for (int n = 0; n < 4; ++n) {
    const int col = wc * 64 + n * 16 + lr;
    const float cv = c[b * Dd + tn * 128 + col];
#pragma unroll
    for (int m = 0; m < 4; ++m)
#pragma unroll
      for (int j = 0; j < 4; ++j)
        base[(size_t)(wr * 64 + m * 16 + lq * 4 + j) * Dd + col] = acc[m][n][j] + cv;
  }
}

// ---------------- launcher ----------------
extern "C" void kernel_launch(void* const* d_in, const int* in_sizes, int n_in,
                              void* d_out, int out_size, void* d_ws, size_t ws_size,
                              hipStream_t stream) {
  const float* X   = (const float*)d_in[0];
  const float* P   = (const float*)d_in[1];
  const float* Wh1 = (const float*)d_in[2];
  const float* bh1 = (const float*)d_in[3];
  const float* Wh2 = (const float*)d_in[4];
  const float* bh2 = (const float*)d_in[5];
  float* Y = (float*)d_out;
  char* ws = (char*)d_ws;

  // workspace layout (bytes)
  u16*   Xp   = (u16*)(ws);                     // 16,777,216
  u16*   XpT  = (u16*)(ws + 16777216);          // 16,777,216
  u16*   WhT1 = (u16*)(ws + 33554432);          //    262,144
  u16*   Wbf2 = (u16*)(ws + 33816576);          //    262,144
  float* G    = (float*)(ws + 34078720);        //  2,097,152
  float* s    = (float*)(ws + 36175872);        //      8,192
  float* c    = (float*)(ws + 36184064);        //      8,192
  u16*   Gb   = (u16*)(ws + 36192256);          //  1,048,576
  u16*   AT   = (u16*)(ws + 37240832);          //  2,097,152
  u16*   HT   = (u16*)(ws + 39337984);          //  1,048,576
  const size_t WS_NEED = 40386560;
  if (ws_size < WS_NEED) return;

  // zero G + s + c (contiguous region)
  hipMemsetAsync(ws + 34078720, 0, 2097152 + 8192 + 8192, stream);

  k_wprep<<<96,   256, 0, stream>>>(Wh1, Wh2, WhT1, Wbf2);
  k_xp   <<<2048, 256, 0, stream>>>(X, P, Xp, XpT, s);
  k_gram <<<256,  256, 0, stream>>>(XpT, G);
  k_gcast<<<256,  256, 0, stream>>>(G, Gb);
  k_pmAT <<<64,   256, 0, stream>>>(WhT1, Gb, bh1, s, AT);
  k_c    <<<2048, 64,  0, stream>>>(AT, bh2, c);
  k_h    <<<32,   256, 0, stream>>>(Wbf2, AT, HT);
  k_y    <<<512,  256, 0, stream>>>(Xp, HT, c, Y);
}

// Round 3
// 98.726 us; speedup vs baseline: 1.3209x; 1.0197x over previous
//
#include <hip/hip_runtime.h>

#define DEV static __device__ __forceinline__

typedef unsigned short u16;
typedef __bf16 bf16_t;
typedef __bf16 bf16x8 __attribute__((ext_vector_type(8)));
typedef float f32x4 __attribute__((ext_vector_type(4)));
typedef u16 u16x8 __attribute__((ext_vector_type(8)));

static constexpr int Bb = 8;     // batch
static constexpr int Nn = 4096;  // tokens per batch
static constexpr int Dd = 256;   // d
static constexpr int DP = 512;   // d_prime

// ---------------- async global->LDS (16B, wave-uniform LDS base + lane*16) ----------------
DEV void gload16(const void* g, void* l) {
  __builtin_amdgcn_global_load_lds(
      (__attribute__((address_space(1))) void*)(unsigned long long)(g),
      (__attribute__((address_space(3))) void*)(unsigned)(unsigned long long)(l),
      16, 0, 0);
}

DEV u16 f2bf(float x) { bf16_t h = (bf16_t)x; return __builtin_bit_cast(u16, h); }
DEV float bf2f(u16 v) { unsigned u = ((unsigned)v) << 16; return __builtin_bit_cast(float, u); }
DEV float gelu_exact(float x) { return 0.5f * x * (1.0f + erff(x * 0.70710678118654752f)); }

// ---------------- 128x128 tile mainloop, operands bf16 stored [rows][K] row-major ----------
// A: M-rows x K ; B: N-rows x K (i.e. B^T layout). 4 waves, each 64x64, 16x16x32 bf16 MFMA.
DEV void gemm_tile(const u16* Ag, int lda, const u16* Bg, int ldb,
                   int k0, int ksteps, u16* ldsA, u16* ldsB, f32x4 acc[4][4]) {
  const int tid  = threadIdx.x;
  const int wave = tid >> 6, lane = tid & 63;
  const int wr = wave >> 1, wc = wave & 1;
  const int lr = lane & 15, lk = (lane >> 4) * 8;
  const int srow = lane >> 2;          // 0..15 row within 16-row chunk
  const int skb  = (lane & 3) * 8;     // k element offset of this lane's 16B

  for (int kt = 0; kt < ksteps; ++kt) {
    const int kk = k0 + kt * 32;
#pragma unroll
    for (int i = 0; i < 2; ++i) {
      const int chunk = wave * 2 + i;          // 8 chunks of 16 rows each
      const int row = chunk * 16 + srow;
      gload16(Ag + (size_t)row * lda + kk + skb, ldsA + chunk * 512);
      gload16(Bg + (size_t)row * ldb + kk + skb, ldsB + chunk * 512);
    }
    asm volatile("s_waitcnt vmcnt(0)" ::: "memory");
    __syncthreads();
    bf16x8 af[4], bfr[4];
#pragma unroll
    for (int m = 0; m < 4; ++m)
      af[m] = *(const bf16x8*)(ldsA + (wr * 64 + m * 16 + lr) * 32 + lk);
#pragma unroll
    for (int n = 0; n < 4; ++n)
      bfr[n] = *(const bf16x8*)(ldsB + (wc * 64 + n * 16 + lr) * 32 + lk);
#pragma unroll
    for (int m = 0; m < 4; ++m)
#pragma unroll
      for (int n = 0; n < 4; ++n)
        acc[m][n] = __builtin_amdgcn_mfma_f32_16x16x32_bf16(af[m], bfr[n], acc[m][n], 0, 0, 0);
    __syncthreads();
  }
}

DEV void acc_zero(f32x4 acc[4][4]) {
#pragma unroll
  for (int m = 0; m < 4; ++m)
#pragma unroll
    for (int n = 0; n < 4; ++n) {
      f32x4 z = {0.f, 0.f, 0.f, 0.f};
      acc[m][n] = z;
    }
}

// ---------------- kernel: zero a float region (float4 per thread) ----------------
__global__ __launch_bounds__(256) void k_zero(float* __restrict__ p, int n4) {
  const int i = blockIdx.x * 256 + threadIdx.x;
  if (i < n4) {
    float4 z = {0.f, 0.f, 0.f, 0.f};
    *(float4*)(p + i * 4) = z;
  }
}

// ---------------- kernel: Xp = bf16(X+P) [b,n,d], XpT [b,d,n], s[b,d] = sum_n Xp ----------
__global__ __launch_bounds__(256) void k_xp(const float* __restrict__ X, const float* __restrict__ P,
                                            u16* __restrict__ Xp, u16* __restrict__ XpT,
                                            float* __restrict__ s) {
  __shared__ u16 lt[64 * 65];
  const int bid = blockIdx.x;
  const int b  = bid >> 8;
  const int nt = (bid >> 2) & 63;
  const int dt = bid & 3;
  const int n0 = nt * 64, d0 = dt * 64;
  const int t = threadIdx.x;
  const int r = t >> 2, c0 = (t & 3) * 16;
  const size_t gbase = ((size_t)(b * Nn + n0 + r)) * Dd + d0 + c0;
  u16x8 lo, hi;
#pragma unroll
  for (int i = 0; i < 4; ++i) {
    float4 xv = *(const float4*)(X + gbase + i * 4);
    float4 pv = *(const float4*)(P + gbase + i * 4);
    u16 a0 = f2bf(xv.x + pv.x), a1 = f2bf(xv.y + pv.y);
    u16 a2 = f2bf(xv.z + pv.z), a3 = f2bf(xv.w + pv.w);
    if (i < 2) { lo[i*4+0]=a0; lo[i*4+1]=a1; lo[i*4+2]=a2; lo[i*4+3]=a3; }
    else       { int q=(i-2)*4; hi[q+0]=a0; hi[q+1]=a1; hi[q+2]=a2; hi[q+3]=a3; }
    lt[r * 65 + c0 + i*4 + 0] = a0; lt[r * 65 + c0 + i*4 + 1] = a1;
    lt[r * 65 + c0 + i*4 + 2] = a2; lt[r * 65 + c0 + i*4 + 3] = a3;
  }
  *(u16x8*)(Xp + gbase)     = lo;
  *(u16x8*)(Xp + gbase + 8) = hi;
  __syncthreads();
  const int dd = t >> 2, nc0 = (t & 3) * 16;
  u16x8 olo, ohi;
  float colsum = 0.f;
#pragma unroll
  for (int i = 0; i < 8; ++i) { olo[i] = lt[(nc0 + i) * 65 + dd]; colsum += bf2f(olo[i]); }
#pragma unroll
  for (int i = 0; i < 8; ++i) { ohi[i] = lt[(nc0 + 8 + i) * 65 + dd]; colsum += bf2f(ohi[i]); }
  const size_t obase = ((size_t)(b * Dd + d0 + dd)) * Nn + n0 + nc0;
  *(u16x8*)(XpT + obase)     = olo;
  *(u16x8*)(XpT + obase + 8) = ohi;
  colsum += __shfl_xor(colsum, 1);
  colsum += __shfl_xor(colsum, 2);
  if ((t & 3) == 0) atomicAdd(s + b * Dd + d0 + dd, colsum);
}

// ---------------- kernel: WhT1[p][d] = bf16(Wh1[d][p]);  Wbf2 = bf16(Wh2) ----------------
__global__ __launch_bounds__(256) void k_wprep(const float* __restrict__ Wh1, const float* __restrict__ Wh2,
                                               u16* __restrict__ WhT1, u16* __restrict__ Wbf2) {
  const int bid = blockIdx.x;
  const int t = threadIdx.x;
  if (bid < 32) {  // transpose Wh1 [256][512] -> WhT1 [512][256]
    __shared__ u16 lt[64 * 65];
    const int rt = (bid >> 3) & 3;      // d tile
    const int ct = bid & 7;             // p tile
    const int r0 = rt * 64, c0t = ct * 64;
    const int r = t >> 2, c0 = (t & 3) * 16;
    const size_t gbase = (size_t)(r0 + r) * DP + c0t + c0;
#pragma unroll
    for (int i = 0; i < 4; ++i) {
      float4 v = *(const float4*)(Wh1 + gbase + i * 4);
      lt[r * 65 + c0 + i*4 + 0] = f2bf(v.x); lt[r * 65 + c0 + i*4 + 1] = f2bf(v.y);
      lt[r * 65 + c0 + i*4 + 2] = f2bf(v.z); lt[r * 65 + c0 + i*4 + 3] = f2bf(v.w);
    }
    __syncthreads();
    const int pp = t >> 2, dc0 = (t & 3) * 16;
    u16x8 olo, ohi;
#pragma unroll
    for (int i = 0; i < 8; ++i) olo[i] = lt[(dc0 + i) * 65 + pp];
#pragma unroll
    for (int i = 0; i < 8; ++i) ohi[i] = lt[(dc0 + 8 + i) * 65 + pp];
    u16* out = WhT1 + (size_t)(c0t + pp) * Dd + r0 + dc0;
    *(u16x8*)(out)     = olo;
    *(u16x8*)(out + 8) = ohi;
  } else {         // straight cast Wh2 -> Wbf2
    const int idx = ((bid - 32) * 256 + t) * 8;
    float4 v0 = *(const float4*)(Wh2 + idx);
    float4 v1 = *(const float4*)(Wh2 + idx + 4);
    u16x8 o;
    o[0]=f2bf(v0.x); o[1]=f2bf(v0.y); o[2]=f2bf(v0.z); o[3]=f2bf(v0.w);
    o[4]=f2bf(v1.x); o[5]=f2bf(v1.y); o[6]=f2bf(v1.z); o[7]=f2bf(v1.w);
    *(u16x8*)(Wbf2 + idx) = o;
  }
}

// ---------------- kernel: G[b] += split-K of XpT[b] @ XpT[b]^T (Gram, f32 atomic) --------
__global__ __launch_bounds__(256) void k_gram(const u16* __restrict__ XpT, float* __restrict__ G) {
  __shared__ __align__(16) u16 ldsA[128 * 32];
  __shared__ __align__(16) u16 ldsB[128 * 32];
  const int bid = blockIdx.x;           // 8b * 2tm * 2tn * 8kc
  const int kc = bid & 7;
  const int tn = (bid >> 3) & 1;
  const int tm = (bid >> 4) & 1;
  const int b  = bid >> 5;
  const u16* Ag = XpT + (size_t)(b * Dd + tm * 128) * Nn;
  const u16* Bg = XpT + (size_t)(b * Dd + tn * 128) * Nn;
  f32x4 acc[4][4];
  acc_zero(acc);
  gemm_tile(Ag, Nn, Bg, Nn, kc * 512, 16, ldsA, ldsB, acc);
  const int tid = threadIdx.x, wave = tid >> 6, lane = tid & 63;
  const int wr = wave >> 1, wc = wave & 1, lr = lane & 15, lq = lane >> 4;
  float* base = G + (size_t)(b * Dd + tm * 128) * Dd + tn * 128;
#pragma unroll
  for (int m = 0; m < 4; ++m)
#pragma unroll
    for (int n = 0; n < 4; ++n)
#pragma unroll
      for (int j = 0; j < 4; ++j)
        atomicAdd(base + (size_t)(wr * 64 + m * 16 + lq * 4 + j) * Dd + wc * 64 + n * 16 + lr,
                  acc[m][n][j]);
}

// ---------------- kernel: Gb = bf16(G) ----------------
__global__ __launch_bounds__(256) void k_gcast(const float* __restrict__ G, u16* __restrict__ Gb) {
  const int idx = (blockIdx.x * 256 + threadIdx.x) * 8;
  float4 v0 = *(const float4*)(G + idx);
  float4 v1 = *(const float4*)(G + idx + 4);
  u16x8 o;
  o[0]=f2bf(v0.x); o[1]=f2bf(v0.y); o[2]=f2bf(v0.z); o[3]=f2bf(v0.w);
  o[4]=f2bf(v1.x); o[5]=f2bf(v1.y); o[6]=f2bf(v1.z); o[7]=f2bf(v1.w);
  *(u16x8*)(Gb + idx) = o;
}

// -------- kernel: AT[b][d][p] = bf16(gelu(Wh1^T G + bh1 ⊗ s)) (Pm computed on the fly) ----
__global__ __launch_bounds__(256) void k_pmAT(const u16* __restrict__ WhT1, const u16* __restrict__ Gb,
                                              const float* __restrict__ bh1, const float* __restrict__ s,
                                              u16* __restrict__ AT) {
  __shared__ __align__(16) u16 ldsA[128 * 32];
  __shared__ __align__(16) u16 ldsB[128 * 32];
  __shared__ __align__(16) u16 ct[128 * 136];
  const int bid = blockIdx.x;        // 8b * 4tm(p) * 2tn(d)
  const int tn = bid & 1;
  const int tm = (bid >> 1) & 3;
  const int b  = bid >> 3;
  const int p0 = tm * 128, d0 = tn * 128;
  const u16* Ag = WhT1 + (size_t)p0 * Dd;                    // rows p, K=d
  const u16* Bg = Gb + (size_t)(b * Dd + d0) * Dd;           // rows d_out, K=d (G symmetric)
  f32x4 acc[4][4];
  acc_zero(acc);
  gemm_tile(Ag, Dd, Bg, Dd, 0, Dd / 32, ldsA, ldsB, acc);
  const int tid = threadIdx.x, wave = tid >> 6, lane = tid & 63;
  const int wr = wave >> 1, wc = wave & 1, lr = lane & 15, lq = lane >> 4;
#pragma unroll
  for (int n = 0; n < 4; ++n) {
    const int col = wc * 64 + n * 16 + lr;              // d within tile
    const float sv = s[b * Dd + d0 + col];
#pragma unroll
    for (int m = 0; m < 4; ++m) {
#pragma unroll
      for (int j = 0; j < 4; ++j) {
        const int row = wr * 64 + m * 16 + lq * 4 + j;  // p within tile
        const float pm = acc[m][n][j] + bh1[p0 + row] * sv;
        ct[col * 136 + row] = f2bf(gelu_exact(pm));
      }
    }
  }
  __syncthreads();
#pragma unroll
  for (int it = 0; it < 8; ++it) {
    const int id = tid + it * 256;
    const int dl = id >> 4, ch = id & 15;
    *(u16x8*)(AT + (size_t)(b * Dd + d0 + dl) * DP + p0 + ch * 8) =
        *(const u16x8*)(ct + dl * 136 + ch * 8);
  }
}

// ---------------- kernel: c[b][d] = sum_p bh2[p] * AT[b][d][p] ----------------
__global__ __launch_bounds__(64) void k_c(const u16* __restrict__ AT, const float* __restrict__ bh2,
                                          float* __restrict__ c) {
  const int bid = blockIdx.x;     // 8b * 256d
  const int b = bid >> 8, d = bid & 255;
  const int lane = threadIdx.x;
  u16x8 v = *(const u16x8*)(AT + (size_t)(b * Dd + d) * DP + lane * 8);
  float sum = 0.f;
#pragma unroll
  for (int i = 0; i < 8; ++i) sum += bh2[lane * 8 + i] * bf2f(v[i]);
#pragma unroll
  for (int off = 1; off < 64; off <<= 1) sum += __shfl_xor(sum, off);
  if (lane == 0) c[b * Dd + d] = sum;
}

// ---------------- kernel: HT[b][d_out][kd] = bf16(Wh2 @ A)^T ----------------
__global__ __launch_bounds__(256) void k_h(const u16* __restrict__ Wbf2, const u16* __restrict__ AT,
                                           u16* __restrict__ HT) {
  __shared__ __align__(16) u16 ldsA[128 * 32];
  __shared__ __align__(16) u16 ldsB[128 * 32];
  __shared__ __align__(16) u16 ct[128 * 136];
  const int bid = blockIdx.x;        // 8b * 2tm(kd) * 2tn(d_out)
  const int tn = bid & 1;
  const int tm = (bid >> 1) & 1;
  const int b  = bid >> 2;
  const int k0 = tm * 128, d0 = tn * 128;
  const u16* Ag = Wbf2 + (size_t)k0 * DP;                    // rows kd, K=p
  const u16* Bg = AT + (size_t)(b * Dd + d0) * DP;           // rows d_out, K=p
  f32x4 acc[4][4];
  acc_zero(acc);
  gemm_tile(Ag, DP, Bg, DP, 0, DP / 32, ldsA, ldsB, acc);
  const int tid = threadIdx.x, wave = tid >> 6, lane = tid & 63;
  const int wr = wave >> 1, wc = wave & 1, lr = lane & 15, lq = lane >> 4;
#pragma unroll
  for (int n = 0; n < 4; ++n) {
    const int col = wc * 64 + n * 16 + lr;              // d_out within tile
#pragma unroll
    for (int m = 0; m < 4; ++m)
#pragma unroll
      for (int j = 0; j < 4; ++j)
        ct[col * 136 + wr * 64 + m * 16 + lq * 4 + j] = f2bf(acc[m][n][j]);
  }
  __syncthreads();
#pragma unroll
  for (int it = 0; it < 8; ++it) {
    const int id = tid + it * 256;
    const int dl = id >> 4, ch = id & 15;
    *(u16x8*)(HT + (size_t)(b * Dd + d0 + dl) * Dd + k0 + ch * 8) =
        *(const u16x8*)(ct + dl * 136 + ch * 8);
  }
}

// ---------------- kernel: Y[b][n][d] = Xp[b] @ H[b] + c[b][d] ----------------
__global__ __launch_bounds__(256) void k_y(const u16* __restrict__ Xp, const u16* __restrict__ HT,
                                           const float* __restrict__ c, float* __restrict__ Y) {
  __shared__ __align__(16) u16 ldsA[128 * 32];
  __shared__ __align__(16) u16 ldsB[128 * 32];
  const int bid = blockIdx.x;      // 8b * 32tm * 2tn
  const int tn = bid & 1;
  const int tm = (bid >> 1) & 31;
  const int b  = bid >> 6;
  const u16* Ag = Xp + (size_t)(b * Nn + tm * 128) * Dd;
  const u16* Bg = HT + (size_t)(b * Dd + tn * 128) * Dd;
  f32x4 acc[4][4];
  acc_zero(acc);
  gemm_tile(Ag, Dd, Bg, Dd, 0, Dd / 32, ldsA, ldsB, acc);
  const int tid = threadIdx.x, wave = tid >> 6, lane = tid & 63;
  const int wr = wave >> 1, wc = wave & 1, lr = lane & 15, lq = lane >> 4;
  float* base = Y + (size_t)(b * Nn + tm * 128) * Dd + tn * 128;
#pragma unroll
  for (int n = 0; n < 4; ++n) {
    const int col = wc * 64 + n * 16 + lr;
    const float cv = c[b * Dd + tn * 128 + col];
#pragma unroll
    for (int m = 0; m < 4; ++m)
#pragma unroll
      for (int j = 0; j < 4; ++j)
        base[(size_t)(wr * 64 + m * 16 + lq * 4 + j) * Dd + col] = acc[m][n][j] + cv;
  }
}

// ---------------- launcher ----------------
extern "C" void kernel_launch(void* const* d_in, const int* in_sizes, int n_in,
                              void* d_out, int out_size, void* d_ws, size_t ws_size,
                              hipStream_t stream) {
  const float* X   = (const float*)d_in[0];
  const float* P   = (const float*)d_in[1];
  const float* Wh1 = (const float*)d_in[2];
  const float* bh1 = (const float*)d_in[3];
  const float* Wh2 = (const float*)d_in[4];
  const float* bh2 = (const float*)d_in[5];
  float* Y = (float*)d_out;
  char* ws = (char*)d_ws;

  // workspace layout (bytes)
  u16*   Xp   = (u16*)(ws);                     // 16,777,216
  u16*   XpT  = (u16*)(ws + 16777216);          // 16,777,216
  u16*   WhT1 = (u16*)(ws + 33554432);          //    262,144
  u16*   Wbf2 = (u16*)(ws + 33816576);          //    262,144
  float* G    = (float*)(ws + 34078720);        //  2,097,152
  float* s    = (float*)(ws + 36175872);        //      8,192
  float* c    = (float*)(ws + 36184064);        //      8,192
  u16*   Gb   = (u16*)(ws + 36192256);          //  1,048,576
  u16*   AT   = (u16*)(ws + 37240832);          //  2,097,152
  u16*   HT   = (u16*)(ws + 39337984);          //  1,048,576
  const size_t WS_NEED = 40386560;
  if (ws_size < WS_NEED) return;

  // zero G + s + c (contiguous region) with our own kernel — rocclr's
  // fillBufferAligned ran at 52 GB/s and cost 41 µs of serial time.
  const int zero_n4 = (2097152 + 8192 + 8192) / 16;   // float4 count = 132,096
  k_zero <<<(zero_n4 + 255) / 256, 256, 0, stream>>>(G, zero_n4);

  k_wprep<<<96,   256, 0, stream>>>(Wh1, Wh2, WhT1, Wbf2);
  k_xp   <<<2048, 256, 0, stream>>>(X, P, Xp, XpT, s);
  k_gram <<<256,  256, 0, stream>>>(XpT, G);
  k_gcast<<<256,  256, 0, stream>>>(G, Gb);
  k_pmAT <<<64,   256, 0, stream>>>(WhT1, Gb, bh1, s, AT);
  k_c    <<<2048, 64,  0, stream>>>(AT, bh2, c);
  k_h    <<<32,   256, 0, stream>>>(Wbf2, AT, HT);
  k_y    <<<512,  256, 0, stream>>>(Xp, HT, c, Y);
}

// Round 4
// 81.313 us; speedup vs baseline: 1.6038x; 1.2142x over previous
//
#include <hip/hip_runtime.h>

#define DEV static __device__ __forceinline__

typedef unsigned short u16;
typedef __bf16 bf16_t;
typedef __bf16 bf16x8 __attribute__((ext_vector_type(8)));
typedef float f32x4 __attribute__((ext_vector_type(4)));
typedef u16 u16x8 __attribute__((ext_vector_type(8)));

static constexpr int Bb = 8;     // batch
static constexpr int Nn = 4096;  // tokens per batch
static constexpr int Dd = 256;   // d
static constexpr int DP = 512;   // d_prime

// ---------------- async global->LDS (16B, wave-uniform LDS base + lane*16) ----------------
DEV void gload16(const void* g, void* l) {
  __builtin_amdgcn_global_load_lds(
      (__attribute__((address_space(1))) void*)(unsigned long long)(g),
      (__attribute__((address_space(3))) void*)(unsigned)(unsigned long long)(l),
      16, 0, 0);
}

DEV u16 f2bf(float x) { bf16_t h = (bf16_t)x; return __builtin_bit_cast(u16, h); }
DEV float bf2f(u16 v) { unsigned u = ((unsigned)v) << 16; return __builtin_bit_cast(float, u); }
DEV float gelu_exact(float x) { return 0.5f * x * (1.0f + erff(x * 0.70710678118654752f)); }

// ---------------- 128x128 tile mainloop, operands bf16 stored [rows][K] row-major ----------
// A: M-rows x K ; B: N-rows x K (i.e. B^T layout). 4 waves, each 64x64, 16x16x32 bf16 MFMA.
DEV void gemm_tile(const u16* Ag, int lda, const u16* Bg, int ldb,
                   int k0, int ksteps, u16* ldsA, u16* ldsB, f32x4 acc[4][4]) {
  const int tid  = threadIdx.x;
  const int wave = tid >> 6, lane = tid & 63;
  const int wr = wave >> 1, wc = wave & 1;
  const int lr = lane & 15, lk = (lane >> 4) * 8;
  const int srow = lane >> 2;          // 0..15 row within 16-row chunk
  const int skb  = (lane & 3) * 8;     // k element offset of this lane's 16B

  for (int kt = 0; kt < ksteps; ++kt) {
    const int kk = k0 + kt * 32;
#pragma unroll
    for (int i = 0; i < 2; ++i) {
      const int chunk = wave * 2 + i;          // 8 chunks of 16 rows each
      const int row = chunk * 16 + srow;
      gload16(Ag + (size_t)row * lda + kk + skb, ldsA + chunk * 512);
      gload16(Bg + (size_t)row * ldb + kk + skb, ldsB + chunk * 512);
    }
    asm volatile("s_waitcnt vmcnt(0)" ::: "memory");
    __syncthreads();
    bf16x8 af[4], bfr[4];
#pragma unroll
    for (int m = 0; m < 4; ++m)
      af[m] = *(const bf16x8*)(ldsA + (wr * 64 + m * 16 + lr) * 32 + lk);
#pragma unroll
    for (int n = 0; n < 4; ++n)
      bfr[n] = *(const bf16x8*)(ldsB + (wc * 64 + n * 16 + lr) * 32 + lk);
#pragma unroll
    for (int m = 0; m < 4; ++m)
#pragma unroll
      for (int n = 0; n < 4; ++n)
        acc[m][n] = __builtin_amdgcn_mfma_f32_16x16x32_bf16(af[m], bfr[n], acc[m][n], 0, 0, 0);
    __syncthreads();
  }
}

DEV void acc_zero(f32x4 acc[4][4]) {
#pragma unroll
  for (int m = 0; m < 4; ++m)
#pragma unroll
    for (int n = 0; n < 4; ++n) {
      f32x4 z = {0.f, 0.f, 0.f, 0.f};
      acc[m][n] = z;
    }
}

// ============ S1 mega-kernel: Xp/XpT/s_part (blocks 0..2047) + Wh prep (2048..2143) ========
__global__ __launch_bounds__(256) void k_s1(const float* __restrict__ X, const float* __restrict__ P,
                                            const float* __restrict__ Wh1, const float* __restrict__ Wh2,
                                            u16* __restrict__ Xp, u16* __restrict__ XpT,
                                            float* __restrict__ s_part,
                                            u16* __restrict__ WhT1, u16* __restrict__ Wbf2) {
  __shared__ u16 lt[64 * 65];
  const int bid = blockIdx.x;
  const int t = threadIdx.x;
  if (bid < 2048) {
    // ---- Xp = bf16(X+P) [b,n,d], XpT [b,d,n], s_part[b][nt][d] = per-tile column sums ----
    const int b  = bid >> 8;
    const int nt = (bid >> 2) & 63;
    const int dt = bid & 3;
    const int n0 = nt * 64, d0 = dt * 64;
    const int r = t >> 2, c0 = (t & 3) * 16;
    const size_t gbase = ((size_t)(b * Nn + n0 + r)) * Dd + d0 + c0;
    u16x8 lo, hi;
#pragma unroll
    for (int i = 0; i < 4; ++i) {
      float4 xv = *(const float4*)(X + gbase + i * 4);
      float4 pv = *(const float4*)(P + gbase + i * 4);
      u16 a0 = f2bf(xv.x + pv.x), a1 = f2bf(xv.y + pv.y);
      u16 a2 = f2bf(xv.z + pv.z), a3 = f2bf(xv.w + pv.w);
      if (i < 2) { lo[i*4+0]=a0; lo[i*4+1]=a1; lo[i*4+2]=a2; lo[i*4+3]=a3; }
      else       { int q=(i-2)*4; hi[q+0]=a0; hi[q+1]=a1; hi[q+2]=a2; hi[q+3]=a3; }
      lt[r * 65 + c0 + i*4 + 0] = a0; lt[r * 65 + c0 + i*4 + 1] = a1;
      lt[r * 65 + c0 + i*4 + 2] = a2; lt[r * 65 + c0 + i*4 + 3] = a3;
    }
    *(u16x8*)(Xp + gbase)     = lo;
    *(u16x8*)(Xp + gbase + 8) = hi;
    __syncthreads();
    const int dd = t >> 2, nc0 = (t & 3) * 16;
    u16x8 olo, ohi;
    float colsum = 0.f;
#pragma unroll
    for (int i = 0; i < 8; ++i) { olo[i] = lt[(nc0 + i) * 65 + dd]; colsum += bf2f(olo[i]); }
#pragma unroll
    for (int i = 0; i < 8; ++i) { ohi[i] = lt[(nc0 + 8 + i) * 65 + dd]; colsum += bf2f(ohi[i]); }
    const size_t obase = ((size_t)(b * Dd + d0 + dd)) * Nn + n0 + nc0;
    *(u16x8*)(XpT + obase)     = olo;
    *(u16x8*)(XpT + obase + 8) = ohi;
    colsum += __shfl_xor(colsum, 1);
    colsum += __shfl_xor(colsum, 2);
    if ((t & 3) == 0) s_part[(size_t)(b * 64 + nt) * Dd + d0 + dd] = colsum;
  } else if (bid < 2048 + 32) {
    // ---- transpose Wh1 [256][512] -> WhT1 [512][256] (bf16) ----
    const int wb = bid - 2048;
    const int rt = (wb >> 3) & 3;       // d tile
    const int ct = wb & 7;              // p tile
    const int r0 = rt * 64, c0t = ct * 64;
    const int r = t >> 2, c0 = (t & 3) * 16;
    const size_t gbase = (size_t)(r0 + r) * DP + c0t + c0;
#pragma unroll
    for (int i = 0; i < 4; ++i) {
      float4 v = *(const float4*)(Wh1 + gbase + i * 4);
      lt[r * 65 + c0 + i*4 + 0] = f2bf(v.x); lt[r * 65 + c0 + i*4 + 1] = f2bf(v.y);
      lt[r * 65 + c0 + i*4 + 2] = f2bf(v.z); lt[r * 65 + c0 + i*4 + 3] = f2bf(v.w);
    }
    __syncthreads();
    const int pp = t >> 2, dc0 = (t & 3) * 16;
    u16x8 olo, ohi;
#pragma unroll
    for (int i = 0; i < 8; ++i) olo[i] = lt[(dc0 + i) * 65 + pp];
#pragma unroll
    for (int i = 0; i < 8; ++i) ohi[i] = lt[(dc0 + 8 + i) * 65 + pp];
    u16* out = WhT1 + (size_t)(c0t + pp) * Dd + r0 + dc0;
    *(u16x8*)(out)     = olo;
    *(u16x8*)(out + 8) = ohi;
  } else {
    // ---- straight cast Wh2 -> Wbf2 (bf16) ----
    const int idx = ((bid - 2048 - 32) * 256 + t) * 8;
    float4 v0 = *(const float4*)(Wh2 + idx);
    float4 v1 = *(const float4*)(Wh2 + idx + 4);
    u16x8 o;
    o[0]=f2bf(v0.x); o[1]=f2bf(v0.y); o[2]=f2bf(v0.z); o[3]=f2bf(v0.w);
    o[4]=f2bf(v1.x); o[5]=f2bf(v1.y); o[6]=f2bf(v1.z); o[7]=f2bf(v1.w);
    *(u16x8*)(Wbf2 + idx) = o;
  }
}

// ======== k_gram: G_part[kc][b][256][256] = XpT[b] @ XpT[b]^T K-slice (plain stores) =======
__global__ __launch_bounds__(256) void k_gram(const u16* __restrict__ XpT, float* __restrict__ G_part) {
  __shared__ __align__(16) u16 ldsA[128 * 32];
  __shared__ __align__(16) u16 ldsB[128 * 32];
  const int bid = blockIdx.x;           // 8b * 2tm * 2tn * 8kc
  const int kc = bid & 7;
  const int tn = (bid >> 3) & 1;
  const int tm = (bid >> 4) & 1;
  const int b  = bid >> 5;
  const u16* Ag = XpT + (size_t)(b * Dd + tm * 128) * Nn;
  const u16* Bg = XpT + (size_t)(b * Dd + tn * 128) * Nn;
  f32x4 acc[4][4];
  acc_zero(acc);
  gemm_tile(Ag, Nn, Bg, Nn, kc * 512, 16, ldsA, ldsB, acc);
  const int tid = threadIdx.x, wave = tid >> 6, lane = tid & 63;
  const int wr = wave >> 1, wc = wave & 1, lr = lane & 15, lq = lane >> 4;
  float* base = G_part + (size_t)kc * (Bb * Dd * Dd) + (size_t)(b * Dd + tm * 128) * Dd + tn * 128;
#pragma unroll
  for (int m = 0; m < 4; ++m)
#pragma unroll
    for (int n = 0; n < 4; ++n)
#pragma unroll
      for (int j = 0; j < 4; ++j)
        base[(size_t)(wr * 64 + m * 16 + lq * 4 + j) * Dd + wc * 64 + n * 16 + lr] = acc[m][n][j];
}

// ==== k_gsum: blocks 0..7 -> s reduce + zero c ; blocks 8..263 -> Gb = bf16(sum slabs) ====
__global__ __launch_bounds__(256) void k_gsum(const float* __restrict__ G_part,
                                              const float* __restrict__ s_part,
                                              u16* __restrict__ Gb, float* __restrict__ s,
                                              float* __restrict__ c) {
  const int bid = blockIdx.x;
  const int t = threadIdx.x;
  if (bid < 8) {
    const int b = bid, d = t;
    float sum = 0.f;
#pragma unroll 8
    for (int nt = 0; nt < 64; ++nt) sum += s_part[(size_t)(b * 64 + nt) * Dd + d];
    s[b * Dd + d] = sum;
    c[b * Dd + d] = 0.f;
  } else {
    const int e = ((bid - 8) * 256 + t) * 8;
    float4 a0 = {0.f,0.f,0.f,0.f}, a1 = {0.f,0.f,0.f,0.f};
#pragma unroll
    for (int k = 0; k < 8; ++k) {
      const float* sp = G_part + (size_t)k * (Bb * Dd * Dd) + e;
      float4 v0 = *(const float4*)(sp);
      float4 v1 = *(const float4*)(sp + 4);
      a0.x += v0.x; a0.y += v0.y; a0.z += v0.z; a0.w += v0.w;
      a1.x += v1.x; a1.y += v1.y; a1.z += v1.z; a1.w += v1.w;
    }
    u16x8 o;
    o[0]=f2bf(a0.x); o[1]=f2bf(a0.y); o[2]=f2bf(a0.z); o[3]=f2bf(a0.w);
    o[4]=f2bf(a1.x); o[5]=f2bf(a1.y); o[6]=f2bf(a1.z); o[7]=f2bf(a1.w);
    *(u16x8*)(Gb + e) = o;
  }
}

// ==== k_pmAT: AT[b][d][p] = bf16(gelu(Wh1^T G + bh1 ⊗ s)); also c[b][d] += bh2·A partial ===
__global__ __launch_bounds__(256) void k_pmAT(const u16* __restrict__ WhT1, const u16* __restrict__ Gb,
                                              const float* __restrict__ bh1, const float* __restrict__ s,
                                              const float* __restrict__ bh2,
                                              u16* __restrict__ AT, float* __restrict__ c) {
  __shared__ __align__(16) u16 ldsA[128 * 32];
  __shared__ __align__(16) u16 ldsB[128 * 32];
  __shared__ __align__(16) u16 ct[128 * 136];
  const int bid = blockIdx.x;        // 8b * 4tm(p) * 2tn(d)
  const int tn = bid & 1;
  const int tm = (bid >> 1) & 3;
  const int b  = bid >> 3;
  const int p0 = tm * 128, d0 = tn * 128;
  const u16* Ag = WhT1 + (size_t)p0 * Dd;                    // rows p, K=d
  const u16* Bg = Gb + (size_t)(b * Dd + d0) * Dd;           // rows d_out, K=d (G symmetric)
  f32x4 acc[4][4];
  acc_zero(acc);
  gemm_tile(Ag, Dd, Bg, Dd, 0, Dd / 32, ldsA, ldsB, acc);
  const int tid = threadIdx.x, wave = tid >> 6, lane = tid & 63;
  const int wr = wave >> 1, wc = wave & 1, lr = lane & 15, lq = lane >> 4;
#pragma unroll
  for (int n = 0; n < 4; ++n) {
    const int col = wc * 64 + n * 16 + lr;              // d within tile
    const float sv = s[b * Dd + d0 + col];
#pragma unroll
    for (int m = 0; m < 4; ++m) {
#pragma unroll
      for (int j = 0; j < 4; ++j) {
        const int row = wr * 64 + m * 16 + lq * 4 + j;  // p within tile
        const float pm = acc[m][n][j] + bh1[p0 + row] * sv;
        ct[col * 136 + row] = f2bf(gelu_exact(pm));
      }
    }
  }
  __syncthreads();
  // AT write
#pragma unroll
  for (int it = 0; it < 8; ++it) {
    const int id = tid + it * 256;
    const int dl = id >> 4, ch = id & 15;
    *(u16x8*)(AT + (size_t)(b * Dd + d0 + dl) * DP + p0 + ch * 8) =
        *(const u16x8*)(ct + dl * 136 + ch * 8);
  }
  // c partial: c[b][d0+col] += sum_p bh2[p0+p] * A[p][d0+col]
  const int ccol = tid >> 1;      // 0..127 d-index within tile
  const int chalf = tid & 1;      // which 64-p half
  float csum = 0.f;
#pragma unroll
  for (int q = 0; q < 8; ++q) {
    u16x8 av = *(const u16x8*)(ct + ccol * 136 + chalf * 64 + q * 8);
#pragma unroll
    for (int i = 0; i < 8; ++i) csum += bh2[p0 + chalf * 64 + q * 8 + i] * bf2f(av[i]);
  }
  csum += __shfl_xor(csum, 1);
  if (chalf == 0) atomicAdd(c + b * Dd + d0 + ccol, csum);
}

// ---------------- kernel: HT[b][d_out][kd] = bf16(Wh2 @ A)^T ----------------
__global__ __launch_bounds__(256) void k_h(const u16* __restrict__ Wbf2, const u16* __restrict__ AT,
                                           u16* __restrict__ HT) {
  __shared__ __align__(16) u16 ldsA[128 * 32];
  __shared__ __align__(16) u16 ldsB[128 * 32];
  __shared__ __align__(16) u16 ct[128 * 136];
  const int bid = blockIdx.x;        // 8b * 2tm(kd) * 2tn(d_out)
  const int tn = bid & 1;
  const int tm = (bid >> 1) & 1;
  const int b  = bid >> 2;
  const int k0 = tm * 128, d0 = tn * 128;
  const u16* Ag = Wbf2 + (size_t)k0 * DP;                    // rows kd, K=p
  const u16* Bg = AT + (size_t)(b * Dd + d0) * DP;           // rows d_out, K=p
  f32x4 acc[4][4];
  acc_zero(acc);
  gemm_tile(Ag, DP, Bg, DP, 0, DP / 32, ldsA, ldsB, acc);
  const int tid = threadIdx.x, wave = tid >> 6, lane = tid & 63;
  const int wr = wave >> 1, wc = wave & 1, lr = lane & 15, lq = lane >> 4;
#pragma unroll
  for (int n = 0; n < 4; ++n) {
    const int col = wc * 64 + n * 16 + lr;              // d_out within tile
#pragma unroll
    for (int m = 0; m < 4; ++m)
#pragma unroll
      for (int j = 0; j < 4; ++j)
        ct[col * 136 + wr * 64 + m * 16 + lq * 4 + j] = f2bf(acc[m][n][j]);
  }
  __syncthreads();
#pragma unroll
  for (int it = 0; it < 8; ++it) {
    const int id = tid + it * 256;
    const int dl = id >> 4, ch = id & 15;
    *(u16x8*)(HT + (size_t)(b * Dd + d0 + dl) * Dd + k0 + ch * 8) =
        *(const u16x8*)(ct + dl * 136 + ch * 8);
  }
}

// ---------------- kernel: Y[b][n][d] = Xp[b] @ H[b] + c[b][d] (XCD-swizzled grid) ---------
__global__ __launch_bounds__(256) void k_y(const u16* __restrict__ Xp, const u16* __restrict__ HT,
                                           const float* __restrict__ c, float* __restrict__ Y) {
  __shared__ __align__(16) u16 ldsA[128 * 32];
  __shared__ __align__(16) u16 ldsB[128 * 32];
  // bijective XCD swizzle: 512 blocks, 8 XCDs, 64 per XCD chunk
  const int bid0 = blockIdx.x;
  const int bid = (bid0 & 7) * 64 + (bid0 >> 3);
  const int tn = bid & 1;
  const int tm = (bid >> 1) & 31;
  const int b  = bid >> 6;
  const u16* Ag = Xp + (size_t)(b * Nn + tm * 128) * Dd;
  const u16* Bg = HT + (size_t)(b * Dd + tn * 128) * Dd;
  f32x4 acc[4][4];
  acc_zero(acc);
  gemm_tile(Ag, Dd, Bg, Dd, 0, Dd / 32, ldsA, ldsB, acc);
  const int tid = threadIdx.x, wave = tid >> 6, lane = tid & 63;
  const int wr = wave >> 1, wc = wave & 1, lr = lane & 15, lq = lane >> 4;
  float* base = Y + (size_t)(b * Nn + tm * 128) * Dd + tn * 128;
#pragma unroll
  for (int n = 0; n < 4; ++n) {
    const int col = wc * 64 + n * 16 + lr;
    const float cv = c[b * Dd + tn * 128 + col];
#pragma unroll
    for (int m = 0; m < 4; ++m)
#pragma unroll
      for (int j = 0; j < 4; ++j)
        base[(size_t)(wr * 64 + m * 16 + lq * 4 + j) * Dd + col] = acc[m][n][j] + cv;
  }
}

// ---------------- launcher ----------------
extern "C" void kernel_launch(void* const* d_in, const int* in_sizes, int n_in,
                              void* d_out, int out_size, void* d_ws, size_t ws_size,
                              hipStream_t stream) {
  const float* X   = (const float*)d_in[0];
  const float* P   = (const float*)d_in[1];
  const float* Wh1 = (const float*)d_in[2];
  const float* bh1 = (const float*)d_in[3];
  const float* Wh2 = (const float*)d_in[4];
  const float* bh2 = (const float*)d_in[5];
  float* Y = (float*)d_out;
  char* ws = (char*)d_ws;

  // workspace layout (bytes)
  u16*   Xp     = (u16*)(ws);                     // 16,777,216
  u16*   XpT    = (u16*)(ws + 16777216);          // 16,777,216
  u16*   WhT1   = (u16*)(ws + 33554432);          //    262,144
  u16*   Wbf2   = (u16*)(ws + 33816576);          //    262,144
  float* G_part = (float*)(ws + 34078720);        // 16,777,216  (8 split-K slabs)
  float* s_part = (float*)(ws + 50855936);        //    524,288
  float* s      = (float*)(ws + 51380224);        //      8,192
  float* c      = (float*)(ws + 51388416);        //      8,192
  u16*   Gb     = (u16*)(ws + 51396608);          //  1,048,576
  u16*   AT     = (u16*)(ws + 52445184);          //  2,097,152
  u16*   HT     = (u16*)(ws + 54542336);          //  1,048,576
  const size_t WS_NEED = 55590912;
  if (ws_size < WS_NEED) return;

  k_s1  <<<2144, 256, 0, stream>>>(X, P, Wh1, Wh2, Xp, XpT, s_part, WhT1, Wbf2);
  k_gram<<<256,  256, 0, stream>>>(XpT, G_part);
  k_gsum<<<264,  256, 0, stream>>>(G_part, s_part, Gb, s, c);
  k_pmAT<<<64,   256, 0, stream>>>(WhT1, Gb, bh1, s, bh2, AT, c);
  k_h   <<<32,   256, 0, stream>>>(Wbf2, AT, HT);
  k_y   <<<512,  256, 0, stream>>>(Xp, HT, c, Y);
}

// Round 5
// 74.439 us; speedup vs baseline: 1.7519x; 1.0923x over previous
//
#include <hip/hip_runtime.h>

#define DEV static __device__ __forceinline__

typedef unsigned short u16;
typedef __bf16 bf16_t;
typedef __bf16 bf16x8 __attribute__((ext_vector_type(8)));
typedef float f32x4 __attribute__((ext_vector_type(4)));
typedef u16 u16x8 __attribute__((ext_vector_type(8)));

static constexpr int Bb = 8;     // batch
static constexpr int Nn = 4096;  // tokens per batch
static constexpr int Dd = 256;   // d
static constexpr int DP = 512;   // d_prime

// ---------------- async global->LDS (16B, wave-uniform LDS base + lane*16) ----------------
DEV void gload16(const void* g, void* l) {
  __builtin_amdgcn_global_load_lds(
      (__attribute__((address_space(1))) void*)(unsigned long long)(g),
      (__attribute__((address_space(3))) void*)(unsigned)(unsigned long long)(l),
      16, 0, 0);
}

DEV u16 f2bf(float x) { bf16_t h = (bf16_t)x; return __builtin_bit_cast(u16, h); }
DEV float bf2f(u16 v) { unsigned u = ((unsigned)v) << 16; return __builtin_bit_cast(float, u); }
DEV float gelu_exact(float x) { return 0.5f * x * (1.0f + erff(x * 0.70710678118654752f)); }

// ------------- 128x128 tile mainloop, 2-phase double-buffered (T3-minimum) ----------------
// A: M-rows x K ; B: N-rows x K (B^T layout). 4 waves, each 64x64, 16x16x32 bf16 MFMA.
// ldsA/ldsB must each hold 2*128*32 u16 (16 KB).
DEV void gemm_tile(const u16* Ag, int lda, const u16* Bg, int ldb,
                   int k0, int ksteps, u16* ldsA, u16* ldsB, f32x4 acc[4][4]) {
  const int tid  = threadIdx.x;
  const int wave = tid >> 6, lane = tid & 63;
  const int wr = wave >> 1, wc = wave & 1;
  const int lr = lane & 15, lk = (lane >> 4) * 8;
  const int srow = lane >> 2;          // 0..15 row within 16-row chunk
  const int skb  = (lane & 3) * 8;     // k element offset of this lane's 16B
  const int c0 = wave * 2, c1 = c0 + 1;
  const size_t ga0 = (size_t)(c0 * 16 + srow) * lda + skb;
  const size_t ga1 = (size_t)(c1 * 16 + srow) * lda + skb;
  const size_t gb0 = (size_t)(c0 * 16 + srow) * ldb + skb;
  const size_t gb1 = (size_t)(c1 * 16 + srow) * ldb + skb;
  u16* la0 = ldsA + c0 * 512; u16* la1 = ldsA + c1 * 512;
  u16* lb0 = ldsB + c0 * 512; u16* lb1 = ldsB + c1 * 512;

  // prologue: stage K-step 0 into buffer 0
  gload16(Ag + ga0 + k0, la0); gload16(Ag + ga1 + k0, la1);
  gload16(Bg + gb0 + k0, lb0); gload16(Bg + gb1 + k0, lb1);
  asm volatile("s_waitcnt vmcnt(0)" ::: "memory");
  __syncthreads();

  int cur = 0;
  for (int kt = 0; kt < ksteps; ++kt) {
    const int nbuf = cur ^ 1;
    if (kt + 1 < ksteps) {               // issue next-step loads BEFORE compute (overlap)
      const int kk = k0 + (kt + 1) * 32;
      gload16(Ag + ga0 + kk, la0 + nbuf * 4096);
      gload16(Ag + ga1 + kk, la1 + nbuf * 4096);
      gload16(Bg + gb0 + kk, lb0 + nbuf * 4096);
      gload16(Bg + gb1 + kk, lb1 + nbuf * 4096);
    }
    const u16* pa = ldsA + cur * 4096;
    const u16* pb = ldsB + cur * 4096;
    bf16x8 af[4], bfr[4];
#pragma unroll
    for (int m = 0; m < 4; ++m)
      af[m] = *(const bf16x8*)(pa + (wr * 64 + m * 16 + lr) * 32 + lk);
#pragma unroll
    for (int n = 0; n < 4; ++n)
      bfr[n] = *(const bf16x8*)(pb + (wc * 64 + n * 16 + lr) * 32 + lk);
#pragma unroll
    for (int m = 0; m < 4; ++m)
#pragma unroll
      for (int n = 0; n < 4; ++n)
        acc[m][n] = __builtin_amdgcn_mfma_f32_16x16x32_bf16(af[m], bfr[n], acc[m][n], 0, 0, 0);
    asm volatile("s_waitcnt vmcnt(0)" ::: "memory");   // next buffer's loads done
    __syncthreads();                                    // all waves done reading cur
    cur = nbuf;
  }
}

DEV void acc_zero(f32x4 acc[4][4]) {
#pragma unroll
  for (int m = 0; m < 4; ++m)
#pragma unroll
    for (int n = 0; n < 4; ++n) {
      f32x4 z = {0.f, 0.f, 0.f, 0.f};
      acc[m][n] = z;
    }
}

// ============ S1 mega-kernel: Xp/XpT/s_part (blocks 0..2047) + Wh prep (2048..2143) ========
__global__ __launch_bounds__(256) void k_s1(const float* __restrict__ X, const float* __restrict__ P,
                                            const float* __restrict__ Wh1, const float* __restrict__ Wh2,
                                            u16* __restrict__ Xp, u16* __restrict__ XpT,
                                            float* __restrict__ s_part,
                                            u16* __restrict__ WhT1, u16* __restrict__ Wbf2) {
  __shared__ u16 lt[64 * 65];
  const int bid = blockIdx.x;
  const int t = threadIdx.x;
  if (bid < 2048) {
    // ---- Xp = bf16(X+P) [b,n,d], XpT [b,d,n], s_part[b][nt][d] = per-tile column sums ----
    const int b  = bid >> 8;
    const int nt = (bid >> 2) & 63;
    const int dt = bid & 3;
    const int n0 = nt * 64, d0 = dt * 64;
    const int r = t >> 2, c0 = (t & 3) * 16;
    const size_t gbase = ((size_t)(b * Nn + n0 + r)) * Dd + d0 + c0;
    u16x8 lo, hi;
#pragma unroll
    for (int i = 0; i < 4; ++i) {
      float4 xv = *(const float4*)(X + gbase + i * 4);
      float4 pv = *(const float4*)(P + gbase + i * 4);
      u16 a0 = f2bf(xv.x + pv.x), a1 = f2bf(xv.y + pv.y);
      u16 a2 = f2bf(xv.z + pv.z), a3 = f2bf(xv.w + pv.w);
      if (i < 2) { lo[i*4+0]=a0; lo[i*4+1]=a1; lo[i*4+2]=a2; lo[i*4+3]=a3; }
      else       { int q=(i-2)*4; hi[q+0]=a0; hi[q+1]=a1; hi[q+2]=a2; hi[q+3]=a3; }
      lt[r * 65 + c0 + i*4 + 0] = a0; lt[r * 65 + c0 + i*4 + 1] = a1;
      lt[r * 65 + c0 + i*4 + 2] = a2; lt[r * 65 + c0 + i*4 + 3] = a3;
    }
    *(u16x8*)(Xp + gbase)     = lo;
    *(u16x8*)(Xp + gbase + 8) = hi;
    __syncthreads();
    const int dd = t >> 2, nc0 = (t & 3) * 16;
    u16x8 olo, ohi;
    float colsum = 0.f;
#pragma unroll
    for (int i = 0; i < 8; ++i) { olo[i] = lt[(nc0 + i) * 65 + dd]; colsum += bf2f(olo[i]); }
#pragma unroll
    for (int i = 0; i < 8; ++i) { ohi[i] = lt[(nc0 + 8 + i) * 65 + dd]; colsum += bf2f(ohi[i]); }
    const size_t obase = ((size_t)(b * Dd + d0 + dd)) * Nn + n0 + nc0;
    *(u16x8*)(XpT + obase)     = olo;
    *(u16x8*)(XpT + obase + 8) = ohi;
    colsum += __shfl_xor(colsum, 1);
    colsum += __shfl_xor(colsum, 2);
    if ((t & 3) == 0) s_part[(size_t)(b * 64 + nt) * Dd + d0 + dd] = colsum;
  } else if (bid < 2048 + 32) {
    // ---- transpose Wh1 [256][512] -> WhT1 [512][256] (bf16) ----
    const int wb = bid - 2048;
    const int rt = (wb >> 3) & 3;       // d tile
    const int ct = wb & 7;              // p tile
    const int r0 = rt * 64, c0t = ct * 64;
    const int r = t >> 2, c0 = (t & 3) * 16;
    const size_t gbase = (size_t)(r0 + r) * DP + c0t + c0;
#pragma unroll
    for (int i = 0; i < 4; ++i) {
      float4 v = *(const float4*)(Wh1 + gbase + i * 4);
      lt[r * 65 + c0 + i*4 + 0] = f2bf(v.x); lt[r * 65 + c0 + i*4 + 1] = f2bf(v.y);
      lt[r * 65 + c0 + i*4 + 2] = f2bf(v.z); lt[r * 65 + c0 + i*4 + 3] = f2bf(v.w);
    }
    __syncthreads();
    const int pp = t >> 2, dc0 = (t & 3) * 16;
    u16x8 olo, ohi;
#pragma unroll
    for (int i = 0; i < 8; ++i) olo[i] = lt[(dc0 + i) * 65 + pp];
#pragma unroll
    for (int i = 0; i < 8; ++i) ohi[i] = lt[(dc0 + 8 + i) * 65 + pp];
    u16* out = WhT1 + (size_t)(c0t + pp) * Dd + r0 + dc0;
    *(u16x8*)(out)     = olo;
    *(u16x8*)(out + 8) = ohi;
  } else {
    // ---- straight cast Wh2 -> Wbf2 (bf16) ----
    const int idx = ((bid - 2048 - 32) * 256 + t) * 8;
    float4 v0 = *(const float4*)(Wh2 + idx);
    float4 v1 = *(const float4*)(Wh2 + idx + 4);
    u16x8 o;
    o[0]=f2bf(v0.x); o[1]=f2bf(v0.y); o[2]=f2bf(v0.z); o[3]=f2bf(v0.w);
    o[4]=f2bf(v1.x); o[5]=f2bf(v1.y); o[6]=f2bf(v1.z); o[7]=f2bf(v1.w);
    *(u16x8*)(Wbf2 + idx) = o;
  }
}

// ======== k_gram: G_part[kc][b][256][256] = XpT[b] @ XpT[b]^T K-slice (plain stores) =======
// XCD-swizzled: 256 blocks -> 32 per XCD = one batch per XCD; XpT[b] (2.1 MB) fits 4 MB L2.
__global__ __launch_bounds__(256) void k_gram(const u16* __restrict__ XpT, float* __restrict__ G_part) {
  __shared__ __align__(16) u16 ldsA[2 * 128 * 32];
  __shared__ __align__(16) u16 ldsB[2 * 128 * 32];
  const int bid0 = blockIdx.x;
  const int bid = (bid0 & 7) * 32 + (bid0 >> 3);   // bijective: 256 = 8 XCD * 32
  const int kc = bid & 7;
  const int tn = (bid >> 3) & 1;
  const int tm = (bid >> 4) & 1;
  const int b  = bid >> 5;
  const u16* Ag = XpT + (size_t)(b * Dd + tm * 128) * Nn;
  const u16* Bg = XpT + (size_t)(b * Dd + tn * 128) * Nn;
  f32x4 acc[4][4];
  acc_zero(acc);
  gemm_tile(Ag, Nn, Bg, Nn, kc * 512, 16, ldsA, ldsB, acc);
  const int tid = threadIdx.x, wave = tid >> 6, lane = tid & 63;
  const int wr = wave >> 1, wc = wave & 1, lr = lane & 15, lq = lane >> 4;
  float* base = G_part + (size_t)kc * (Bb * Dd * Dd) + (size_t)(b * Dd + tm * 128) * Dd + tn * 128;
#pragma unroll
  for (int m = 0; m < 4; ++m)
#pragma unroll
    for (int n = 0; n < 4; ++n)
#pragma unroll
      for (int j = 0; j < 4; ++j)
        base[(size_t)(wr * 64 + m * 16 + lq * 4 + j) * Dd + wc * 64 + n * 16 + lr] = acc[m][n][j];
}

// ==== k_gsum: blocks 0..7 -> s reduce + zero c ; blocks 8..263 -> Gb = bf16(sum slabs) ====
__global__ __launch_bounds__(256) void k_gsum(const float* __restrict__ G_part,
                                              const float* __restrict__ s_part,
                                              u16* __restrict__ Gb, float* __restrict__ s,
                                              float* __restrict__ c) {
  const int bid = blockIdx.x;
  const int t = threadIdx.x;
  if (bid < 8) {
    const int b = bid, d = t;
    float sum = 0.f;
#pragma unroll 8
    for (int nt = 0; nt < 64; ++nt) sum += s_part[(size_t)(b * 64 + nt) * Dd + d];
    s[b * Dd + d] = sum;
    c[b * Dd + d] = 0.f;
  } else {
    const int e = ((bid - 8) * 256 + t) * 8;
    float4 a0 = {0.f,0.f,0.f,0.f}, a1 = {0.f,0.f,0.f,0.f};
#pragma unroll
    for (int k = 0; k < 8; ++k) {
      const float* sp = G_part + (size_t)k * (Bb * Dd * Dd) + e;
      float4 v0 = *(const float4*)(sp);
      float4 v1 = *(const float4*)(sp + 4);
      a0.x += v0.x; a0.y += v0.y; a0.z += v0.z; a0.w += v0.w;
      a1.x += v1.x; a1.y += v1.y; a1.z += v1.z; a1.w += v1.w;
    }
    u16x8 o;
    o[0]=f2bf(a0.x); o[1]=f2bf(a0.y); o[2]=f2bf(a0.z); o[3]=f2bf(a0.w);
    o[4]=f2bf(a1.x); o[5]=f2bf(a1.y); o[6]=f2bf(a1.z); o[7]=f2bf(a1.w);
    *(u16x8*)(Gb + e) = o;
  }
}

// ==== k_pmAT: AT[b][d][p] = bf16(gelu(Wh1^T G + bh1 ⊗ s)); also c[b][d] += bh2·A partial ===
__global__ __launch_bounds__(256) void k_pmAT(const u16* __restrict__ WhT1, const u16* __restrict__ Gb,
                                              const float* __restrict__ bh1, const float* __restrict__ s,
                                              const float* __restrict__ bh2,
                                              u16* __restrict__ AT, float* __restrict__ c) {
  __shared__ __align__(16) u16 ldsA[2 * 128 * 32];
  __shared__ __align__(16) u16 ldsB[2 * 128 * 32];
  __shared__ __align__(16) u16 ct[128 * 136];
  const int bid = blockIdx.x;        // 8b * 4tm(p) * 2tn(d)
  const int tn = bid & 1;
  const int tm = (bid >> 1) & 3;
  const int b  = bid >> 3;
  const int p0 = tm * 128, d0 = tn * 128;
  const u16* Ag = WhT1 + (size_t)p0 * Dd;                    // rows p, K=d
  const u16* Bg = Gb + (size_t)(b * Dd + d0) * Dd;           // rows d_out, K=d (G symmetric)
  f32x4 acc[4][4];
  acc_zero(acc);
  gemm_tile(Ag, Dd, Bg, Dd, 0, Dd / 32, ldsA, ldsB, acc);
  const int tid = threadIdx.x, wave = tid >> 6, lane = tid & 63;
  const int wr = wave >> 1, wc = wave & 1, lr = lane & 15, lq = lane >> 4;
#pragma unroll
  for (int n = 0; n < 4; ++n) {
    const int col = wc * 64 + n * 16 + lr;              // d within tile
    const float sv = s[b * Dd + d0 + col];
#pragma unroll
    for (int m = 0; m < 4; ++m) {
#pragma unroll
      for (int j = 0; j < 4; ++j) {
        const int row = wr * 64 + m * 16 + lq * 4 + j;  // p within tile
        const float pm = acc[m][n][j] + bh1[p0 + row] * sv;
        ct[col * 136 + row] = f2bf(gelu_exact(pm));
      }
    }
  }
  __syncthreads();
  // AT write
#pragma unroll
  for (int it = 0; it < 8; ++it) {
    const int id = tid + it * 256;
    const int dl = id >> 4, ch = id & 15;
    *(u16x8*)(AT + (size_t)(b * Dd + d0 + dl) * DP + p0 + ch * 8) =
        *(const u16x8*)(ct + dl * 136 + ch * 8);
  }
  // c partial: c[b][d0+col] += sum_p bh2[p0+p] * A[p][d0+col]
  const int ccol = tid >> 1;      // 0..127 d-index within tile
  const int chalf = tid & 1;      // which 64-p half
  float csum = 0.f;
#pragma unroll
  for (int q = 0; q < 8; ++q) {
    u16x8 av = *(const u16x8*)(ct + ccol * 136 + chalf * 64 + q * 8);
#pragma unroll
    for (int i = 0; i < 8; ++i) csum += bh2[p0 + chalf * 64 + q * 8 + i] * bf2f(av[i]);
  }
  csum += __shfl_xor(csum, 1);
  if (chalf == 0) atomicAdd(c + b * Dd + d0 + ccol, csum);
}

// ---------------- kernel: HT[b][d_out][kd] = bf16(Wh2 @ A)^T ----------------
__global__ __launch_bounds__(256) void k_h(const u16* __restrict__ Wbf2, const u16* __restrict__ AT,
                                           u16* __restrict__ HT) {
  __shared__ __align__(16) u16 ldsA[2 * 128 * 32];
  __shared__ __align__(16) u16 ldsB[2 * 128 * 32];
  __shared__ __align__(16) u16 ct[128 * 136];
  const int bid = blockIdx.x;        // 8b * 2tm(kd) * 2tn(d_out)
  const int tn = bid & 1;
  const int tm = (bid >> 1) & 1;
  const int b  = bid >> 2;
  const int k0 = tm * 128, d0 = tn * 128;
  const u16* Ag = Wbf2 + (size_t)k0 * DP;                    // rows kd, K=p
  const u16* Bg = AT + (size_t)(b * Dd + d0) * DP;           // rows d_out, K=p
  f32x4 acc[4][4];
  acc_zero(acc);
  gemm_tile(Ag, DP, Bg, DP, 0, DP / 32, ldsA, ldsB, acc);
  const int tid = threadIdx.x, wave = tid >> 6, lane = tid & 63;
  const int wr = wave >> 1, wc = wave & 1, lr = lane & 15, lq = lane >> 4;
#pragma unroll
  for (int n = 0; n < 4; ++n) {
    const int col = wc * 64 + n * 16 + lr;              // d_out within tile
#pragma unroll
    for (int m = 0; m < 4; ++m)
#pragma unroll
      for (int j = 0; j < 4; ++j)
        ct[col * 136 + wr * 64 + m * 16 + lq * 4 + j] = f2bf(acc[m][n][j]);
  }
  __syncthreads();
#pragma unroll
  for (int it = 0; it < 8; ++it) {
    const int id = tid + it * 256;
    const int dl = id >> 4, ch = id & 15;
    *(u16x8*)(HT + (size_t)(b * Dd + d0 + dl) * Dd + k0 + ch * 8) =
        *(const u16x8*)(ct + dl * 136 + ch * 8);
  }
}

// ---------------- kernel: Y[b][n][d] = Xp[b] @ H[b] + c[b][d] (XCD-swizzled grid) ---------
__global__ __launch_bounds__(256) void k_y(const u16* __restrict__ Xp, const u16* __restrict__ HT,
                                           const float* __restrict__ c, float* __restrict__ Y) {
  __shared__ __align__(16) u16 ldsA[2 * 128 * 32];
  __shared__ __align__(16) u16 ldsB[2 * 128 * 32];
  // bijective XCD swizzle: 512 blocks, 8 XCDs, 64 per XCD chunk -> one batch per XCD
  const int bid0 = blockIdx.x;
  const int bid = (bid0 & 7) * 64 + (bid0 >> 3);
  const int tn = bid & 1;
  const int tm = (bid >> 1) & 31;
  const int b  = bid >> 6;
  const u16* Ag = Xp + (size_t)(b * Nn + tm * 128) * Dd;
  const u16* Bg = HT + (size_t)(b * Dd + tn * 128) * Dd;
  f32x4 acc[4][4];
  acc_zero(acc);
  gemm_tile(Ag, Dd, Bg, Dd, 0, Dd / 32, ldsA, ldsB, acc);
  const int tid = threadIdx.x, wave = tid >> 6, lane = tid & 63;
  const int wr = wave >> 1, wc = wave & 1, lr = lane & 15, lq = lane >> 4;
  float* base = Y + (size_t)(b * Nn + tm * 128) * Dd + tn * 128;
#pragma unroll
  for (int n = 0; n < 4; ++n) {
    const int col = wc * 64 + n * 16 + lr;
    const float cv = c[b * Dd + tn * 128 + col];
#pragma unroll
    for (int m = 0; m < 4; ++m)
#pragma unroll
      for (int j = 0; j < 4; ++j)
        base[(size_t)(wr * 64 + m * 16 + lq * 4 + j) * Dd + col] = acc[m][n][j] + cv;
  }
}

// ---------------- launcher ----------------
extern "C" void kernel_launch(void* const* d_in, const int* in_sizes, int n_in,
                              void* d_out, int out_size, void* d_ws, size_t ws_size,
                              hipStream_t stream) {
  const float* X   = (const float*)d_in[0];
  const float* P   = (const float*)d_in[1];
  const float* Wh1 = (const float*)d_in[2];
  const float* bh1 = (const float*)d_in[3];
  const float* Wh2 = (const float*)d_in[4];
  const float* bh2 = (const float*)d_in[5];
  float* Y = (float*)d_out;
  char* ws = (char*)d_ws;

  // workspace layout (bytes)
  u16*   Xp     = (u16*)(ws);                     // 16,777,216
  u16*   XpT    = (u16*)(ws + 16777216);          // 16,777,216
  u16*   WhT1   = (u16*)(ws + 33554432);          //    262,144
  u16*   Wbf2   = (u16*)(ws + 33816576);          //    262,144
  float* G_part = (float*)(ws + 34078720);        // 16,777,216  (8 split-K slabs)
  float* s_part = (float*)(ws + 50855936);        //    524,288
  float* s      = (float*)(ws + 51380224);        //      8,192
  float* c      = (float*)(ws + 51388416);        //      8,192
  u16*   Gb     = (u16*)(ws + 51396608);          //  1,048,576
  u16*   AT     = (u16*)(ws + 52445184);          //  2,097,152
  u16*   HT     = (u16*)(ws + 54542336);          //  1,048,576
  const size_t WS_NEED = 55590912;
  if (ws_size < WS_NEED) return;

  k_s1  <<<2144, 256, 0, stream>>>(X, P, Wh1, Wh2, Xp, XpT, s_part, WhT1, Wbf2);
  k_gram<<<256,  256, 0, stream>>>(XpT, G_part);
  k_gsum<<<264,  256, 0, stream>>>(G_part, s_part, Gb, s, c);
  k_pmAT<<<64,   256, 0, stream>>>(WhT1, Gb, bh1, s, bh2, AT, c);
  k_h   <<<32,   256, 0, stream>>>(Wbf2, AT, HT);
  k_y   <<<512,  256, 0, stream>>>(Xp, HT, c, Y);
}